// Round 1
// baseline (1135.456 us; speedup 1.0000x reference)
//
#include <hip/hip_runtime.h>
#include <math.h>

// Problem constants (from reference)
#define NHEAD 2
#define NDIM  64
#define HD    128   // NHEAD*NDIM
#define NGRAPH 64
#define NCLS  5
#define NEG_SLOPE 0.2f

// ---------------- CSR build ----------------

__global__ void k_deg(const int* __restrict__ dst, int* __restrict__ deg, int E) {
    int i = blockIdx.x * blockDim.x + threadIdx.x;
    if (i < E) atomicAdd(&deg[dst[i]], 1);
}

// single-block exclusive scan: ptr[0]=0, ptr[i+1]=sum(deg[0..i])
__global__ void k_scan(const int* __restrict__ deg, int* __restrict__ ptr, int n) {
    __shared__ int wsums[16];
    __shared__ int carry_s;
    const int tid = threadIdx.x, lane = tid & 63, wid = tid >> 6;
    if (tid == 0) carry_s = 0;
    __syncthreads();
    for (int base = 0; base < n; base += 1024) {
        int i = base + tid;
        int v = (i < n) ? deg[i] : 0;
        int x = v;
        #pragma unroll
        for (int off = 1; off < 64; off <<= 1) {
            int t = __shfl_up(x, off, 64);
            if (lane >= off) x += t;
        }
        if (lane == 63) wsums[wid] = x;
        __syncthreads();
        if (wid == 0) {
            int s = (lane < 16) ? wsums[lane] : 0;
            #pragma unroll
            for (int off = 1; off < 16; off <<= 1) {
                int t = __shfl_up(s, off, 64);
                if (lane >= off) s += t;
            }
            if (lane < 16) wsums[lane] = s;
        }
        __syncthreads();
        int waveoff = (wid > 0) ? wsums[wid - 1] : 0;
        int inc = x + waveoff + carry_s;
        if (i < n) ptr[i + 1] = inc;
        __syncthreads();
        if (tid == 1023) carry_s = inc;
        __syncthreads();
    }
    if (threadIdx.x == 0) ptr[0] = 0;
}

__global__ void k_scatter(const int* __restrict__ src, const int* __restrict__ dst,
                          const int* __restrict__ ptr, int* __restrict__ fill,
                          int* __restrict__ csr, int E) {
    int i = blockIdx.x * blockDim.x + threadIdx.x;
    if (i < E) {
        int d = dst[i];
        int pos = atomicAdd(&fill[d], 1);
        csr[ptr[d] + pos] = src[i];
    }
}

// ---------------- GEMMs ----------------

// layer 1: x[N,4] @ W[4,128] -> out[N,128]
__global__ void k_gemm1(const float* __restrict__ x, const float* __restrict__ W,
                        float* __restrict__ out, int N) {
    int idx = blockIdx.x * blockDim.x + threadIdx.x;
    if (idx >= N * HD) return;
    int node = idx >> 7, col = idx & 127;
    float4 xv = *(const float4*)&x[node * 4];
    out[idx] = xv.x * W[col] + xv.y * W[128 + col] + xv.z * W[256 + col] + xv.w * W[384 + col];
}

// layers 2-4: in[N,128] @ W[128,128] -> out[N,128]
// block=256 threads, 32 nodes/block; K tiled in 2 slabs of 64 (LDS = 32KB + 8KB)
__global__ __launch_bounds__(256) void k_gemm128(const float* __restrict__ in,
                                                 const float* __restrict__ W,
                                                 float* __restrict__ out, int N) {
    __shared__ float Wl[64 * 128];   // 32 KB: K-slab of W
    __shared__ float Il[32 * 64];    // 8 KB: 32 nodes x K-slab
    const int tid = threadIdx.x;
    const int nbase = blockIdx.x * 32;
    const int c0 = (tid & 31) << 2;   // output col base (4 cols)
    const int r0 = tid >> 5;          // node sub-row 0..7 (nodes r0+8i)

    float acc[4][4];
    #pragma unroll
    for (int i = 0; i < 4; i++)
        #pragma unroll
        for (int j = 0; j < 4; j++) acc[i][j] = 0.f;

    for (int kk = 0; kk < 128; kk += 64) {
        // stage W rows kk..kk+63 (2048 float4)
        for (int i = tid; i < 2048; i += 256)
            ((float4*)Wl)[i] = ((const float4*)(W + kk * 128))[i];
        // stage 32 node-rows, cols kk..kk+63 (512 float4)
        for (int i = tid; i < 512; i += 256) {
            int r = i >> 4;
            int c4 = (i & 15) << 2;
            int node = nbase + r;
            float4 v = make_float4(0.f, 0.f, 0.f, 0.f);
            if (node < N) v = *(const float4*)&in[(size_t)node * HD + kk + c4];
            *(float4*)&Il[r * 64 + c4] = v;
        }
        __syncthreads();
        for (int k = 0; k < 64; k += 4) {
            float4 w0 = *(float4*)&Wl[(k + 0) * 128 + c0];
            float4 w1 = *(float4*)&Wl[(k + 1) * 128 + c0];
            float4 w2 = *(float4*)&Wl[(k + 2) * 128 + c0];
            float4 w3 = *(float4*)&Wl[(k + 3) * 128 + c0];
            #pragma unroll
            for (int i = 0; i < 4; i++) {
                float4 a = *(float4*)&Il[(r0 + 8 * i) * 64 + k];
                acc[i][0] += a.x * w0.x + a.y * w1.x + a.z * w2.x + a.w * w3.x;
                acc[i][1] += a.x * w0.y + a.y * w1.y + a.z * w2.y + a.w * w3.y;
                acc[i][2] += a.x * w0.z + a.y * w1.z + a.z * w2.z + a.w * w3.z;
                acc[i][3] += a.x * w0.w + a.y * w1.w + a.z * w2.w + a.w * w3.w;
            }
        }
        __syncthreads();
    }
    #pragma unroll
    for (int i = 0; i < 4; i++) {
        int node = nbase + r0 + 8 * i;
        if (node < N) {
            float4 o = make_float4(acc[i][0], acc[i][1], acc[i][2], acc[i][3]);
            *(float4*)&out[(size_t)node * HD + c0] = o;
        }
    }
}

// ---------------- per-node alpha (dot with attention vectors) ----------------
// one wave per (node, head)
__global__ void k_alpha(const float* __restrict__ h, const float* __restrict__ asrc,
                        const float* __restrict__ adst, float* __restrict__ oas,
                        float* __restrict__ oad, int N) {
    int gw = (blockIdx.x * blockDim.x + threadIdx.x) >> 6;
    int lane = threadIdx.x & 63;
    int n = gw >> 1, head = gw & 1;
    if (n >= N) return;
    float v = h[(size_t)n * HD + head * NDIM + lane];
    float s = v * asrc[head * NDIM + lane];
    float t = v * adst[head * NDIM + lane];
    #pragma unroll
    for (int off = 32; off > 0; off >>= 1) {
        s += __shfl_xor(s, off);
        t += __shfl_xor(t, off);
    }
    if (lane == 0) {
        oas[n * 2 + head] = s;
        oad[n * 2 + head] = t;
    }
}

// ---------------- fused edge-softmax + aggregation + bias + relu ----------------
// one wave per (node, head); lane = feature dim; online softmax over incoming edges
__global__ void k_agg(const float* __restrict__ h, const float* __restrict__ oas,
                      const float* __restrict__ oad, const int* __restrict__ ptr,
                      const int* __restrict__ csr, const float* __restrict__ bias,
                      float* __restrict__ out, int N) {
    int gw = (blockIdx.x * blockDim.x + threadIdx.x) >> 6;
    int lane = threadIdx.x & 63;
    int n = gw >> 1, head = gw & 1;
    if (n >= N) return;
    float adn = oad[n * 2 + head];
    int beg = ptr[n], end = ptr[n + 1];
    float m = -INFINITY, l = 0.f, acc = 0.f;
    const float* hbase = h + head * NDIM + lane;
    for (int j = beg; j < end; ++j) {
        int s = csr[j];
        float e = oas[s * 2 + head] + adn;
        e = (e >= 0.f) ? e : NEG_SLOPE * e;
        float hm = fmaxf(m, e);
        float sc = __expf(m - hm);
        float p = __expf(e - hm);
        float hv = hbase[(size_t)s * HD];
        l = l * sc + p;
        acc = acc * sc + p * hv;
        m = hm;
    }
    float v = acc / (l + 1e-16f);
    v += bias[head * NDIM + lane];
    out[(size_t)n * HD + head * NDIM + lane] = fmaxf(v, 0.f);
}

// ---------------- pooling ----------------

__global__ void k_count(const int* __restrict__ batch, int* __restrict__ gcount, int N) {
    int i = blockIdx.x * blockDim.x + threadIdx.x;
    if (i < N) atomicAdd(&gcount[batch[i]], 1);
}

// block = 128 threads (col), 128 nodes per block; batch sorted -> run-length accumulate
__global__ void k_pool(const float* __restrict__ feat, const int* __restrict__ batch,
                       float* __restrict__ pooled, int N) {
    int col = threadIdx.x;
    int n0 = blockIdx.x * 128;
    int n1 = min(n0 + 128, N);
    float acc = 0.f;
    int curg = -1;
    for (int n = n0; n < n1; ++n) {
        int g = batch[n];
        if (g != curg) {
            if (curg >= 0) atomicAdd(&pooled[curg * HD + col], acc);
            acc = 0.f;
            curg = g;
        }
        acc += feat[(size_t)n * HD + col];
    }
    if (curg >= 0) atomicAdd(&pooled[curg * HD + col], acc);
}

__global__ void k_final(const float* __restrict__ pooled, const int* __restrict__ gcount,
                        const float* __restrict__ lw, const float* __restrict__ lb,
                        float* __restrict__ out) {
    int tid = threadIdx.x;
    if (tid >= NGRAPH * NCLS) return;
    int g = tid / NCLS, c = tid % NCLS;
    float cnt = fmaxf((float)gcount[g], 1.f);
    const float* p = pooled + g * HD;
    float sum = 0.f;
    for (int k = 0; k < HD; ++k)
        sum += p[k] * lw[k * NCLS + c];
    float z = lb[c] + sum / cnt;
    out[tid] = 1.f / (1.f + __expf(-z));
}

// ---------------- launch ----------------

static inline size_t al256(size_t x) { return (x + 255) & ~(size_t)255; }

extern "C" void kernel_launch(void* const* d_in, const int* in_sizes, int n_in,
                              void* d_out, int out_size, void* d_ws, size_t ws_size,
                              hipStream_t stream) {
    const int N = in_sizes[0] / 4;   // x is [N,4]
    const int E = in_sizes[1] / 2;   // edge_index is [2,E]

    const float* x     = (const float*)d_in[0];
    const int*   esrc  = (const int*)d_in[1];
    const int*   edst  = esrc + E;
    const int*   batch = (const int*)d_in[2];
    const float* Wl[4]  = {(const float*)d_in[3],  (const float*)d_in[7],
                           (const float*)d_in[11], (const float*)d_in[15]};
    const float* asr[4] = {(const float*)d_in[4],  (const float*)d_in[8],
                           (const float*)d_in[12], (const float*)d_in[16]};
    const float* ads[4] = {(const float*)d_in[5],  (const float*)d_in[9],
                           (const float*)d_in[13], (const float*)d_in[17]};
    const float* bs[4]  = {(const float*)d_in[6],  (const float*)d_in[10],
                           (const float*)d_in[14], (const float*)d_in[18]};
    const float* lin_w = (const float*)d_in[19];
    const float* lin_b = (const float*)d_in[20];
    float* out = (float*)d_out;

    // workspace layout (zero-region first)
    char* w = (char*)d_ws;
    size_t off = 0;
    auto alloc = [&](size_t bytes) -> void* {
        void* p = w + off;
        off = al256(off + bytes);
        return p;
    };
    int*   deg    = (int*)alloc((size_t)N * 4);
    int*   fill   = (int*)alloc((size_t)N * 4);
    int*   gcount = (int*)alloc((size_t)NGRAPH * 4);
    float* pooled = (float*)alloc((size_t)NGRAPH * HD * 4);
    size_t zbytes = off;
    int*   ptr    = (int*)alloc((size_t)(N + 1) * 4);
    int*   csr    = (int*)alloc((size_t)E * 4);
    float* hbuf   = (float*)alloc((size_t)N * HD * 4);
    float* feat   = (float*)alloc((size_t)N * HD * 4);
    float* a_src  = (float*)alloc((size_t)N * 2 * 4);
    float* a_dst  = (float*)alloc((size_t)N * 2 * 4);
    (void)ws_size; (void)n_in; (void)out_size;

    hipMemsetAsync(d_ws, 0, zbytes, stream);

    // CSR by dst (once; reused by all 4 layers)
    k_deg<<<(E + 255) / 256, 256, 0, stream>>>(edst, deg, E);
    k_scan<<<1, 1024, 0, stream>>>(deg, ptr, N);
    k_scatter<<<(E + 255) / 256, 256, 0, stream>>>(esrc, edst, ptr, fill, csr, E);

    const int wave_blocks = (N * 2 + 3) / 4;  // 4 waves per 256-thread block

    for (int layer = 0; layer < 4; ++layer) {
        if (layer == 0)
            k_gemm1<<<(N * HD + 255) / 256, 256, 0, stream>>>(x, Wl[0], hbuf, N);
        else
            k_gemm128<<<(N + 31) / 32, 256, 0, stream>>>(feat, Wl[layer], hbuf, N);
        k_alpha<<<wave_blocks, 256, 0, stream>>>(hbuf, asr[layer], ads[layer], a_src, a_dst, N);
        k_agg<<<wave_blocks, 256, 0, stream>>>(hbuf, a_src, a_dst, ptr, csr, bs[layer], feat, N);
    }

    k_count<<<(N + 255) / 256, 256, 0, stream>>>(batch, gcount, N);
    k_pool<<<(N + 127) / 128, 128, 0, stream>>>(feat, batch, pooled, N);
    k_final<<<1, 320, 0, stream>>>(pooled, gcount, lin_w, lin_b, out);
}

// Round 2
// 711.444 us; speedup vs baseline: 1.5960x; 1.5960x over previous
//
#include <hip/hip_runtime.h>
#include <math.h>

// Problem constants (from reference)
#define NHEAD 2
#define NDIM  64
#define HD    128   // NHEAD*NDIM
#define NGRAPH 64
#define NCLS  5
#define NEG_SLOPE 0.2f

// ---------------- CSR build ----------------

__global__ void k_deg(const int* __restrict__ dst, int* __restrict__ deg, int E) {
    int i = blockIdx.x * blockDim.x + threadIdx.x;
    if (i < E) atomicAdd(&deg[dst[i]], 1);
}

// single-block exclusive scan: ptr[0]=0, ptr[i+1]=sum(deg[0..i])
__global__ void k_scan(const int* __restrict__ deg, int* __restrict__ ptr, int n) {
    __shared__ int wsums[16];
    __shared__ int carry_s;
    const int tid = threadIdx.x, lane = tid & 63, wid = tid >> 6;
    if (tid == 0) carry_s = 0;
    __syncthreads();
    for (int base = 0; base < n; base += 1024) {
        int i = base + tid;
        int v = (i < n) ? deg[i] : 0;
        int x = v;
        #pragma unroll
        for (int off = 1; off < 64; off <<= 1) {
            int t = __shfl_up(x, off, 64);
            if (lane >= off) x += t;
        }
        if (lane == 63) wsums[wid] = x;
        __syncthreads();
        if (wid == 0) {
            int s = (lane < 16) ? wsums[lane] : 0;
            #pragma unroll
            for (int off = 1; off < 16; off <<= 1) {
                int t = __shfl_up(s, off, 64);
                if (lane >= off) s += t;
            }
            if (lane < 16) wsums[lane] = s;
        }
        __syncthreads();
        int waveoff = (wid > 0) ? wsums[wid - 1] : 0;
        int inc = x + waveoff + carry_s;
        if (i < n) ptr[i + 1] = inc;
        __syncthreads();
        if (tid == 1023) carry_s = inc;
        __syncthreads();
    }
    if (threadIdx.x == 0) ptr[0] = 0;
}

__global__ void k_scatter(const int* __restrict__ src, const int* __restrict__ dst,
                          const int* __restrict__ ptr, int* __restrict__ fill,
                          int* __restrict__ csr, int E) {
    int i = blockIdx.x * blockDim.x + threadIdx.x;
    if (i < E) {
        int d = dst[i];
        int pos = atomicAdd(&fill[d], 1);
        csr[ptr[d] + pos] = src[i];
    }
}

// ---------------- GEMMs ----------------

// layer 1: x[N,4] @ W[4,128] -> out[N,128]
__global__ void k_gemm1(const float* __restrict__ x, const float* __restrict__ W,
                        float* __restrict__ out, int N) {
    int idx = blockIdx.x * blockDim.x + threadIdx.x;
    if (idx >= N * HD) return;
    int node = idx >> 7, col = idx & 127;
    float4 xv = *(const float4*)&x[node * 4];
    out[idx] = xv.x * W[col] + xv.y * W[128 + col] + xv.z * W[256 + col] + xv.w * W[384 + col];
}

// layers 2-4: in[N,128] @ W[128,128] -> out[N,128]
// block=256 threads, 32 nodes/block; K tiled in 2 slabs of 64 (LDS = 32KB + 8KB)
__global__ __launch_bounds__(256) void k_gemm128(const float* __restrict__ in,
                                                 const float* __restrict__ W,
                                                 float* __restrict__ out, int N) {
    __shared__ float Wl[64 * 128];   // 32 KB: K-slab of W
    __shared__ float Il[32 * 64];    // 8 KB: 32 nodes x K-slab
    const int tid = threadIdx.x;
    const int nbase = blockIdx.x * 32;
    const int c0 = (tid & 31) << 2;   // output col base (4 cols)
    const int r0 = tid >> 5;          // node sub-row 0..7 (nodes r0+8i)

    float acc[4][4];
    #pragma unroll
    for (int i = 0; i < 4; i++)
        #pragma unroll
        for (int j = 0; j < 4; j++) acc[i][j] = 0.f;

    for (int kk = 0; kk < 128; kk += 64) {
        // stage W rows kk..kk+63 (2048 float4)
        for (int i = tid; i < 2048; i += 256)
            ((float4*)Wl)[i] = ((const float4*)(W + kk * 128))[i];
        // stage 32 node-rows, cols kk..kk+63 (512 float4)
        for (int i = tid; i < 512; i += 256) {
            int r = i >> 4;
            int c4 = (i & 15) << 2;
            int node = nbase + r;
            float4 v = make_float4(0.f, 0.f, 0.f, 0.f);
            if (node < N) v = *(const float4*)&in[(size_t)node * HD + kk + c4];
            *(float4*)&Il[r * 64 + c4] = v;
        }
        __syncthreads();
        for (int k = 0; k < 64; k += 4) {
            float4 w0 = *(float4*)&Wl[(k + 0) * 128 + c0];
            float4 w1 = *(float4*)&Wl[(k + 1) * 128 + c0];
            float4 w2 = *(float4*)&Wl[(k + 2) * 128 + c0];
            float4 w3 = *(float4*)&Wl[(k + 3) * 128 + c0];
            #pragma unroll
            for (int i = 0; i < 4; i++) {
                float4 a = *(float4*)&Il[(r0 + 8 * i) * 64 + k];
                acc[i][0] += a.x * w0.x + a.y * w1.x + a.z * w2.x + a.w * w3.x;
                acc[i][1] += a.x * w0.y + a.y * w1.y + a.z * w2.y + a.w * w3.y;
                acc[i][2] += a.x * w0.z + a.y * w1.z + a.z * w2.z + a.w * w3.z;
                acc[i][3] += a.x * w0.w + a.y * w1.w + a.z * w2.w + a.w * w3.w;
            }
        }
        __syncthreads();
    }
    #pragma unroll
    for (int i = 0; i < 4; i++) {
        int node = nbase + r0 + 8 * i;
        if (node < N) {
            float4 o = make_float4(acc[i][0], acc[i][1], acc[i][2], acc[i][3]);
            *(float4*)&out[(size_t)node * HD + c0] = o;
        }
    }
}

// ---------------- per-node alpha (dot with attention vectors) ----------------
// one wave per node, BOTH heads: lane covers dims (2*lane, 2*lane+1); head = lane>>5
__global__ void k_alpha(const float* __restrict__ h, const float* __restrict__ asrc,
                        const float* __restrict__ adst, float* __restrict__ oas,
                        float* __restrict__ oad, int N) {
    int n = (blockIdx.x * blockDim.x + threadIdx.x) >> 6;
    int lane = threadIdx.x & 63;
    if (n >= N) return;
    float2 v = *(const float2*)&h[(size_t)n * HD + lane * 2];
    float2 av = *(const float2*)&asrc[lane * 2];
    float2 dv = *(const float2*)&adst[lane * 2];
    float s = v.x * av.x + v.y * av.y;
    float t = v.x * dv.x + v.y * dv.y;
    // reduce within each 32-lane half (one head per half)
    #pragma unroll
    for (int off = 16; off > 0; off >>= 1) {
        s += __shfl_xor(s, off);
        t += __shfl_xor(t, off);
    }
    if ((lane & 31) == 0) {
        int head = lane >> 5;
        oas[n * 2 + head] = s;
        oad[n * 2 + head] = t;
    }
}

// ---------------- fused edge-softmax + aggregation + bias + relu ----------------
// one wave per node, both heads; lane covers dims (2*lane, 2*lane+1); head = lane>>5
// online softmax over incoming edges, zero atomics
__global__ void k_agg(const float* __restrict__ h, const float* __restrict__ oas,
                      const float* __restrict__ oad, const int* __restrict__ ptr,
                      const int* __restrict__ csr, const float* __restrict__ bias,
                      float* __restrict__ out, int N) {
    int n = (blockIdx.x * blockDim.x + threadIdx.x) >> 6;
    int lane = threadIdx.x & 63;
    if (n >= N) return;
    float2 adn = *(const float2*)&oad[n * 2];
    int beg = ptr[n], end = ptr[n + 1];
    float m = -INFINITY, l = 0.f;
    float accx = 0.f, accy = 0.f;
    const int head = lane >> 5;
    const float* hb = h + lane * 2;
    int s = (beg < end) ? csr[beg] : 0;
    for (int j = beg; j < end; ++j) {
        int sn = (j + 1 < end) ? csr[j + 1] : 0;
        float2 as = *(const float2*)&oas[s * 2];
        float e0 = as.x + adn.x; e0 = (e0 >= 0.f) ? e0 : NEG_SLOPE * e0;
        float e1 = as.y + adn.y; e1 = (e1 >= 0.f) ? e1 : NEG_SLOPE * e1;
        float e = head ? e1 : e0;
        float hm = fmaxf(m, e);
        float sc = __expf(m - hm);
        float p = __expf(e - hm);
        float2 hv = *(const float2*)&hb[(size_t)s * HD];
        l = l * sc + p;
        accx = accx * sc + p * hv.x;
        accy = accy * sc + p * hv.y;
        m = hm;
        s = sn;
    }
    float inv = 1.f / (l + 1e-16f);
    float2 b = *(const float2*)&bias[lane * 2];
    float ox = fmaxf(accx * inv + b.x, 0.f);
    float oy = fmaxf(accy * inv + b.y, 0.f);
    *(float2*)&out[(size_t)n * HD + lane * 2] = make_float2(ox, oy);
}

// ---------------- pooling (fused graph-size count) ----------------
// block = 128 threads (col), 128 nodes per block; batch sorted -> run-length accumulate
__global__ void k_pool(const float* __restrict__ feat, const int* __restrict__ batch,
                       float* __restrict__ pooled, int* __restrict__ gcount, int N) {
    int col = threadIdx.x;
    int n0 = blockIdx.x * 128;
    int n1 = min(n0 + 128, N);
    float acc = 0.f;
    int curg = -1, runlen = 0;
    for (int n = n0; n < n1; ++n) {
        int g = batch[n];
        if (g != curg) {
            if (curg >= 0) {
                atomicAdd(&pooled[curg * HD + col], acc);
                if (col == 0) atomicAdd(&gcount[curg], runlen);
            }
            acc = 0.f; runlen = 0;
            curg = g;
        }
        acc += feat[(size_t)n * HD + col];
        runlen++;
    }
    if (curg >= 0) {
        atomicAdd(&pooled[curg * HD + col], acc);
        if (col == 0) atomicAdd(&gcount[curg], runlen);
    }
}

__global__ void k_final(const float* __restrict__ pooled, const int* __restrict__ gcount,
                        const float* __restrict__ lw, const float* __restrict__ lb,
                        float* __restrict__ out) {
    int tid = threadIdx.x;
    if (tid >= NGRAPH * NCLS) return;
    int g = tid / NCLS, c = tid % NCLS;
    float cnt = fmaxf((float)gcount[g], 1.f);
    const float* p = pooled + g * HD;
    float sum = 0.f;
    for (int k = 0; k < HD; ++k)
        sum += p[k] * lw[k * NCLS + c];
    float z = lb[c] + sum / cnt;
    out[tid] = 1.f / (1.f + __expf(-z));
}

// ---------------- launch ----------------

static inline size_t al256(size_t x) { return (x + 255) & ~(size_t)255; }

extern "C" void kernel_launch(void* const* d_in, const int* in_sizes, int n_in,
                              void* d_out, int out_size, void* d_ws, size_t ws_size,
                              hipStream_t stream) {
    const int N = in_sizes[0] / 4;   // x is [N,4]
    const int E = in_sizes[1] / 2;   // edge_index is [2,E]

    const float* x     = (const float*)d_in[0];
    const int*   esrc  = (const int*)d_in[1];
    const int*   edst  = esrc + E;
    const int*   batch = (const int*)d_in[2];
    const float* Wl[4]  = {(const float*)d_in[3],  (const float*)d_in[7],
                           (const float*)d_in[11], (const float*)d_in[15]};
    const float* asr[4] = {(const float*)d_in[4],  (const float*)d_in[8],
                           (const float*)d_in[12], (const float*)d_in[16]};
    const float* ads[4] = {(const float*)d_in[5],  (const float*)d_in[9],
                           (const float*)d_in[13], (const float*)d_in[17]};
    const float* bs[4]  = {(const float*)d_in[6],  (const float*)d_in[10],
                           (const float*)d_in[14], (const float*)d_in[18]};
    const float* lin_w = (const float*)d_in[19];
    const float* lin_b = (const float*)d_in[20];
    float* out = (float*)d_out;

    // workspace layout (zero-region first)
    char* w = (char*)d_ws;
    size_t off = 0;
    auto alloc = [&](size_t bytes) -> void* {
        void* p = w + off;
        off = al256(off + bytes);
        return p;
    };
    int*   deg    = (int*)alloc((size_t)N * 4);
    int*   fill   = (int*)alloc((size_t)N * 4);
    int*   gcount = (int*)alloc((size_t)NGRAPH * 4);
    float* pooled = (float*)alloc((size_t)NGRAPH * HD * 4);
    size_t zbytes = off;
    int*   ptr    = (int*)alloc((size_t)(N + 1) * 4);
    int*   csr    = (int*)alloc((size_t)E * 4);
    float* hbuf   = (float*)alloc((size_t)N * HD * 4);
    float* feat   = (float*)alloc((size_t)N * HD * 4);
    float* a_src  = (float*)alloc((size_t)N * 2 * 4);
    float* a_dst  = (float*)alloc((size_t)N * 2 * 4);
    (void)ws_size; (void)n_in; (void)out_size;

    hipMemsetAsync(d_ws, 0, zbytes, stream);

    // CSR by dst (once; reused by all 4 layers)
    k_deg<<<(E + 255) / 256, 256, 0, stream>>>(edst, deg, E);
    k_scan<<<1, 1024, 0, stream>>>(deg, ptr, N);
    k_scatter<<<(E + 255) / 256, 256, 0, stream>>>(esrc, edst, ptr, fill, csr, E);

    const int node_wave_blocks = (N + 3) / 4;  // one wave per node, 4 waves/block

    for (int layer = 0; layer < 4; ++layer) {
        if (layer == 0)
            k_gemm1<<<(N * HD + 255) / 256, 256, 0, stream>>>(x, Wl[0], hbuf, N);
        else
            k_gemm128<<<(N + 31) / 32, 256, 0, stream>>>(feat, Wl[layer], hbuf, N);
        k_alpha<<<node_wave_blocks, 256, 0, stream>>>(hbuf, asr[layer], ads[layer], a_src, a_dst, N);
        k_agg<<<node_wave_blocks, 256, 0, stream>>>(hbuf, a_src, a_dst, ptr, csr, bs[layer], feat, N);
    }

    k_pool<<<(N + 127) / 128, 128, 0, stream>>>(feat, batch, pooled, gcount, N);
    k_final<<<1, 320, 0, stream>>>(pooled, gcount, lin_w, lin_b, out);
}

// Round 3
// 566.969 us; speedup vs baseline: 2.0027x; 1.2548x over previous
//
#include <hip/hip_runtime.h>
#include <math.h>

// Problem constants (from reference)
#define NHEAD 2
#define NDIM  64
#define HD    128   // NHEAD*NDIM
#define NGRAPH 64
#define NCLS  5
#define NEG_SLOPE 0.2f

typedef __attribute__((ext_vector_type(8))) short bf16x8;
typedef __attribute__((ext_vector_type(4))) float f32x4;

static __device__ __forceinline__ unsigned short f2bf(float f) {
    unsigned int u = __float_as_uint(f);
    u = (u + 0x7fff + ((u >> 16) & 1)) >> 16;   // round-to-nearest-even
    return (unsigned short)u;
}
static __device__ __forceinline__ float bf2f(unsigned short b) {
    return __uint_as_float((unsigned int)b << 16);
}

// ---------------- CSR build ----------------

__global__ void k_deg(const int* __restrict__ dst, int* __restrict__ deg, int E) {
    int i = blockIdx.x * blockDim.x + threadIdx.x;
    if (i < E) atomicAdd(&deg[dst[i]], 1);
}

// single-block exclusive scan: ptr[0]=0, ptr[i+1]=sum(deg[0..i])
__global__ void k_scan(const int* __restrict__ deg, int* __restrict__ ptr, int n) {
    __shared__ int wsums[16];
    __shared__ int carry_s;
    const int tid = threadIdx.x, lane = tid & 63, wid = tid >> 6;
    if (tid == 0) carry_s = 0;
    __syncthreads();
    for (int base = 0; base < n; base += 1024) {
        int i = base + tid;
        int v = (i < n) ? deg[i] : 0;
        int x = v;
        #pragma unroll
        for (int off = 1; off < 64; off <<= 1) {
            int t = __shfl_up(x, off, 64);
            if (lane >= off) x += t;
        }
        if (lane == 63) wsums[wid] = x;
        __syncthreads();
        if (wid == 0) {
            int s = (lane < 16) ? wsums[lane] : 0;
            #pragma unroll
            for (int off = 1; off < 16; off <<= 1) {
                int t = __shfl_up(s, off, 64);
                if (lane >= off) s += t;
            }
            if (lane < 16) wsums[lane] = s;
        }
        __syncthreads();
        int waveoff = (wid > 0) ? wsums[wid - 1] : 0;
        int inc = x + waveoff + carry_s;
        if (i < n) ptr[i + 1] = inc;
        __syncthreads();
        if (tid == 1023) carry_s = inc;
        __syncthreads();
    }
    if (threadIdx.x == 0) ptr[0] = 0;
}

__global__ void k_scatter(const int* __restrict__ src, const int* __restrict__ dst,
                          const int* __restrict__ ptr, int* __restrict__ fill,
                          int* __restrict__ csr, int E) {
    int i = blockIdx.x * blockDim.x + threadIdx.x;
    if (i < E) {
        int d = dst[i];
        int pos = atomicAdd(&fill[d], 1);
        csr[ptr[d] + pos] = src[i];
    }
}

// ---------------- weight prep: fp32 W[k][n] -> bf16 Wt[n][k] for layers 2-4 ------

__global__ void k_prepw(const float* __restrict__ W2, const float* __restrict__ W3,
                        const float* __restrict__ W4, unsigned short* __restrict__ Wt) {
    int idx = blockIdx.x * blockDim.x + threadIdx.x;
    if (idx >= 3 * HD * HD) return;
    int l = idx / (HD * HD), rem = idx % (HD * HD);
    int n = rem >> 7, k = rem & 127;
    const float* W = (l == 0) ? W2 : (l == 1) ? W3 : W4;
    Wt[idx] = f2bf(W[k * HD + n]);
}

// ---------------- GEMMs ----------------

// layer 1: x[N,4] @ W[4,128] -> h bf16 [N,128]
__global__ void k_gemm1(const float* __restrict__ x, const float* __restrict__ W,
                        unsigned short* __restrict__ out, int N) {
    int idx = blockIdx.x * blockDim.x + threadIdx.x;
    if (idx >= N * HD) return;
    int node = idx >> 7, col = idx & 127;
    float4 xv = *(const float4*)&x[node * 4];
    float v = xv.x * W[col] + xv.y * W[128 + col] + xv.z * W[256 + col] + xv.w * W[384 + col];
    out[idx] = f2bf(v);
}

// layers 2-4: A_bf16[N,128] @ W -> h bf16 [N,128], via MFMA 16x16x32
// block = 256 threads (4 waves), 128 rows/block; full K=128 staged in LDS.
// wave w computes rows [w*32, w*32+32) x all 128 cols.
#define LDA 136   // padded LDS row stride (elements)
__global__ __launch_bounds__(256) void k_gemm_mfma(const unsigned short* __restrict__ A,
                                                   const unsigned short* __restrict__ Wt,
                                                   unsigned short* __restrict__ out, int N) {
    __shared__ unsigned short As[128 * LDA];
    __shared__ unsigned short Ws[128 * LDA];
    const int tid = threadIdx.x;
    const int nbase = blockIdx.x * 128;
    const int lane = tid & 63, w = tid >> 6;
    const int l15 = lane & 15, quad = lane >> 4;
    const int koff = quad * 8;

    // stage A rows (zero-padded past N) and Wt, 16B chunks
    for (int c = tid; c < 2048; c += 256) {
        int row = c >> 4, k8 = (c & 15) << 3;
        int g = nbase + row;
        uint4 v = make_uint4(0, 0, 0, 0);
        if (g < N) v = *(const uint4*)&A[(size_t)g * HD + k8];
        *(uint4*)&As[row * LDA + k8] = v;
    }
    for (int c = tid; c < 2048; c += 256) {
        int row = c >> 4, k8 = (c & 15) << 3;
        *(uint4*)&Ws[row * LDA + k8] = *(const uint4*)&Wt[row * HD + k8];
    }
    __syncthreads();

    f32x4 acc0[8], acc1[8];
    #pragma unroll
    for (int c = 0; c < 8; ++c) { acc0[c] = (f32x4)(0.f); acc1[c] = (f32x4)(0.f); }

    const int r0 = w * 32 + l15;
    #pragma unroll
    for (int ks = 0; ks < 4; ++ks) {
        bf16x8 a0 = *(const bf16x8*)&As[r0 * LDA + ks * 32 + koff];
        bf16x8 a1 = *(const bf16x8*)&As[(r0 + 16) * LDA + ks * 32 + koff];
        #pragma unroll
        for (int c = 0; c < 8; ++c) {
            bf16x8 b = *(const bf16x8*)&Ws[(c * 16 + l15) * LDA + ks * 32 + koff];
            acc0[c] = __builtin_amdgcn_mfma_f32_16x16x32_bf16(a0, b, acc0[c], 0, 0, 0);
            acc1[c] = __builtin_amdgcn_mfma_f32_16x16x32_bf16(a1, b, acc1[c], 0, 0, 0);
        }
    }

    // D layout: row = quad*4 + reg, col = c*16 + l15
    #pragma unroll
    for (int i = 0; i < 2; ++i) {
        int rowb = nbase + w * 32 + i * 16 + quad * 4;
        #pragma unroll
        for (int c = 0; c < 8; ++c) {
            f32x4 v = i ? acc1[c] : acc0[c];
            int col = c * 16 + l15;
            #pragma unroll
            for (int r = 0; r < 4; ++r) {
                int row = rowb + r;
                if (row < N) out[(size_t)row * HD + col] = f2bf(v[r]);
            }
        }
    }
}

// ---------------- per-node alpha (dot with attention vectors) ----------------
// one wave per node, BOTH heads: lane covers dims (2*lane, 2*lane+1); head = lane>>5
__global__ void k_alpha(const unsigned short* __restrict__ h, const float* __restrict__ asrc,
                        const float* __restrict__ adst, float* __restrict__ oas,
                        float* __restrict__ oad, int N) {
    int n = (blockIdx.x * blockDim.x + threadIdx.x) >> 6;
    int lane = threadIdx.x & 63;
    if (n >= N) return;
    ushort2 uv = *(const ushort2*)&h[(size_t)n * HD + lane * 2];
    float vx = bf2f(uv.x), vy = bf2f(uv.y);
    float2 av = *(const float2*)&asrc[lane * 2];
    float2 dv = *(const float2*)&adst[lane * 2];
    float s = vx * av.x + vy * av.y;
    float t = vx * dv.x + vy * dv.y;
    #pragma unroll
    for (int off = 16; off > 0; off >>= 1) {
        s += __shfl_xor(s, off);
        t += __shfl_xor(t, off);
    }
    if ((lane & 31) == 0) {
        int head = lane >> 5;
        oas[n * 2 + head] = s;
        oad[n * 2 + head] = t;
    }
}

// ---------------- fused edge-softmax + aggregation + bias + relu ----------------
// one wave per node, both heads; lane covers dims (2*lane, 2*lane+1); head = lane>>5
__global__ void k_agg(const unsigned short* __restrict__ h, const float* __restrict__ oas,
                      const float* __restrict__ oad, const int* __restrict__ ptr,
                      const int* __restrict__ csr, const float* __restrict__ bias,
                      unsigned short* __restrict__ out, int N) {
    int n = (blockIdx.x * blockDim.x + threadIdx.x) >> 6;
    int lane = threadIdx.x & 63;
    if (n >= N) return;
    float2 adn = *(const float2*)&oad[n * 2];
    int beg = ptr[n], end = ptr[n + 1];
    float m = -INFINITY, l = 0.f;
    float accx = 0.f, accy = 0.f;
    const int head = lane >> 5;
    const unsigned short* hb = h + lane * 2;
    int s = (beg < end) ? csr[beg] : 0;
    for (int j = beg; j < end; ++j) {
        int sn = (j + 1 < end) ? csr[j + 1] : 0;
        float2 as = *(const float2*)&oas[s * 2];
        float e0 = as.x + adn.x; e0 = (e0 >= 0.f) ? e0 : NEG_SLOPE * e0;
        float e1 = as.y + adn.y; e1 = (e1 >= 0.f) ? e1 : NEG_SLOPE * e1;
        float e = head ? e1 : e0;
        float hm = fmaxf(m, e);
        float sc = __expf(m - hm);
        float p = __expf(e - hm);
        ushort2 uv = *(const ushort2*)&hb[(size_t)s * HD];
        l = l * sc + p;
        accx = accx * sc + p * bf2f(uv.x);
        accy = accy * sc + p * bf2f(uv.y);
        m = hm;
        s = sn;
    }
    float inv = 1.f / (l + 1e-16f);
    float2 b = *(const float2*)&bias[lane * 2];
    float ox = fmaxf(accx * inv + b.x, 0.f);
    float oy = fmaxf(accy * inv + b.y, 0.f);
    unsigned int packed = (unsigned int)f2bf(ox) | ((unsigned int)f2bf(oy) << 16);
    *(unsigned int*)&out[(size_t)n * HD + lane * 2] = packed;
}

// ---------------- pooling (fused graph-size count) ----------------
__global__ void k_pool(const unsigned short* __restrict__ feat, const int* __restrict__ batch,
                       float* __restrict__ pooled, int* __restrict__ gcount, int N) {
    int col = threadIdx.x;
    int n0 = blockIdx.x * 128;
    int n1 = min(n0 + 128, N);
    float acc = 0.f;
    int curg = -1, runlen = 0;
    for (int n = n0; n < n1; ++n) {
        int g = batch[n];
        if (g != curg) {
            if (curg >= 0) {
                atomicAdd(&pooled[curg * HD + col], acc);
                if (col == 0) atomicAdd(&gcount[curg], runlen);
            }
            acc = 0.f; runlen = 0;
            curg = g;
        }
        acc += bf2f(feat[(size_t)n * HD + col]);
        runlen++;
    }
    if (curg >= 0) {
        atomicAdd(&pooled[curg * HD + col], acc);
        if (col == 0) atomicAdd(&gcount[curg], runlen);
    }
}

__global__ void k_final(const float* __restrict__ pooled, const int* __restrict__ gcount,
                        const float* __restrict__ lw, const float* __restrict__ lb,
                        float* __restrict__ out) {
    int tid = threadIdx.x;
    if (tid >= NGRAPH * NCLS) return;
    int g = tid / NCLS, c = tid % NCLS;
    float cnt = fmaxf((float)gcount[g], 1.f);
    const float* p = pooled + g * HD;
    float sum = 0.f;
    for (int k = 0; k < HD; ++k)
        sum += p[k] * lw[k * NCLS + c];
    float z = lb[c] + sum / cnt;
    out[tid] = 1.f / (1.f + __expf(-z));
}

// ---------------- launch ----------------

static inline size_t al256(size_t x) { return (x + 255) & ~(size_t)255; }

extern "C" void kernel_launch(void* const* d_in, const int* in_sizes, int n_in,
                              void* d_out, int out_size, void* d_ws, size_t ws_size,
                              hipStream_t stream) {
    const int N = in_sizes[0] / 4;   // x is [N,4]
    const int E = in_sizes[1] / 2;   // edge_index is [2,E]

    const float* x     = (const float*)d_in[0];
    const int*   esrc  = (const int*)d_in[1];
    const int*   edst  = esrc + E;
    const int*   batch = (const int*)d_in[2];
    const float* Wl[4]  = {(const float*)d_in[3],  (const float*)d_in[7],
                           (const float*)d_in[11], (const float*)d_in[15]};
    const float* asr[4] = {(const float*)d_in[4],  (const float*)d_in[8],
                           (const float*)d_in[12], (const float*)d_in[16]};
    const float* ads[4] = {(const float*)d_in[5],  (const float*)d_in[9],
                           (const float*)d_in[13], (const float*)d_in[17]};
    const float* bs[4]  = {(const float*)d_in[6],  (const float*)d_in[10],
                           (const float*)d_in[14], (const float*)d_in[18]};
    const float* lin_w = (const float*)d_in[19];
    const float* lin_b = (const float*)d_in[20];
    float* out = (float*)d_out;

    // workspace layout (zero-region first)
    char* w = (char*)d_ws;
    size_t off = 0;
    auto alloc = [&](size_t bytes) -> void* {
        void* p = w + off;
        off = al256(off + bytes);
        return p;
    };
    int*   deg    = (int*)alloc((size_t)N * 4);
    int*   fill   = (int*)alloc((size_t)N * 4);
    int*   gcount = (int*)alloc((size_t)NGRAPH * 4);
    float* pooled = (float*)alloc((size_t)NGRAPH * HD * 4);
    size_t zbytes = off;
    int*   ptr    = (int*)alloc((size_t)(N + 1) * 4);
    int*   csr    = (int*)alloc((size_t)E * 4);
    unsigned short* hbuf = (unsigned short*)alloc((size_t)N * HD * 2);
    unsigned short* feat = (unsigned short*)alloc((size_t)N * HD * 2);
    unsigned short* Wt   = (unsigned short*)alloc((size_t)3 * HD * HD * 2);
    float* a_src  = (float*)alloc((size_t)N * 2 * 4);
    float* a_dst  = (float*)alloc((size_t)N * 2 * 4);
    (void)ws_size; (void)n_in; (void)out_size;

    hipMemsetAsync(d_ws, 0, zbytes, stream);

    // weight prep + CSR by dst (reused by all 4 layers)
    k_prepw<<<(3 * HD * HD + 255) / 256, 256, 0, stream>>>(Wl[1], Wl[2], Wl[3], Wt);
    k_deg<<<(E + 255) / 256, 256, 0, stream>>>(edst, deg, E);
    k_scan<<<1, 1024, 0, stream>>>(deg, ptr, N);
    k_scatter<<<(E + 255) / 256, 256, 0, stream>>>(esrc, edst, ptr, fill, csr, E);

    const int node_wave_blocks = (N + 3) / 4;  // one wave per node, 4 waves/block

    for (int layer = 0; layer < 4; ++layer) {
        if (layer == 0)
            k_gemm1<<<(N * HD + 255) / 256, 256, 0, stream>>>(x, Wl[0], hbuf, N);
        else
            k_gemm_mfma<<<(N + 127) / 128, 256, 0, stream>>>(feat, Wt + (size_t)(layer - 1) * HD * HD, hbuf, N);
        k_alpha<<<node_wave_blocks, 256, 0, stream>>>(hbuf, asr[layer], ads[layer], a_src, a_dst, N);
        k_agg<<<node_wave_blocks, 256, 0, stream>>>(hbuf, a_src, a_dst, ptr, csr, bs[layer], feat, N);
    }

    k_pool<<<(N + 127) / 128, 128, 0, stream>>>(feat, batch, pooled, gcount, N);
    k_final<<<1, 320, 0, stream>>>(pooled, gcount, lin_w, lin_b, out);
}

// Round 4
// 500.512 us; speedup vs baseline: 2.2686x; 1.1328x over previous
//
#include <hip/hip_runtime.h>
#include <math.h>

// Problem constants (from reference)
#define NHEAD 2
#define NDIM  64
#define HD    128   // NHEAD*NDIM
#define NGRAPH 64
#define NCLS  5
#define NEG_SLOPE 0.2f

typedef __attribute__((ext_vector_type(8))) short bf16x8;
typedef __attribute__((ext_vector_type(4))) float f32x4;

static __device__ __forceinline__ unsigned short f2bf(float f) {
    unsigned int u = __float_as_uint(f);
    u = (u + 0x7fff + ((u >> 16) & 1)) >> 16;   // round-to-nearest-even
    return (unsigned short)u;
}
static __device__ __forceinline__ float bf2f(unsigned short b) {
    return __uint_as_float((unsigned int)b << 16);
}
static __device__ __forceinline__ float rdlane_f(float v, int j) {
    return __uint_as_float(__builtin_amdgcn_readlane(__float_as_uint(v), j));
}

// ---------------- CSR build ----------------

__global__ void k_deg(const int* __restrict__ dst, int* __restrict__ deg, int E) {
    int i = blockIdx.x * blockDim.x + threadIdx.x;
    if (i < E) atomicAdd(&deg[dst[i]], 1);
}

// single-block exclusive scan: ptr[0]=0, ptr[i+1]=sum(deg[0..i])
__global__ void k_scan(const int* __restrict__ deg, int* __restrict__ ptr, int n) {
    __shared__ int wsums[16];
    __shared__ int carry_s;
    const int tid = threadIdx.x, lane = tid & 63, wid = tid >> 6;
    if (tid == 0) carry_s = 0;
    __syncthreads();
    for (int base = 0; base < n; base += 1024) {
        int i = base + tid;
        int v = (i < n) ? deg[i] : 0;
        int x = v;
        #pragma unroll
        for (int off = 1; off < 64; off <<= 1) {
            int t = __shfl_up(x, off, 64);
            if (lane >= off) x += t;
        }
        if (lane == 63) wsums[wid] = x;
        __syncthreads();
        if (wid == 0) {
            int s = (lane < 16) ? wsums[lane] : 0;
            #pragma unroll
            for (int off = 1; off < 16; off <<= 1) {
                int t = __shfl_up(s, off, 64);
                if (lane >= off) s += t;
            }
            if (lane < 16) wsums[lane] = s;
        }
        __syncthreads();
        int waveoff = (wid > 0) ? wsums[wid - 1] : 0;
        int inc = x + waveoff + carry_s;
        if (i < n) ptr[i + 1] = inc;
        __syncthreads();
        if (tid == 1023) carry_s = inc;
        __syncthreads();
    }
    if (threadIdx.x == 0) ptr[0] = 0;
}

__global__ void k_scatter(const int* __restrict__ src, const int* __restrict__ dst,
                          const int* __restrict__ ptr, int* __restrict__ fill,
                          int* __restrict__ csr, int E) {
    int i = blockIdx.x * blockDim.x + threadIdx.x;
    if (i < E) {
        int d = dst[i];
        int pos = atomicAdd(&fill[d], 1);
        csr[ptr[d] + pos] = src[i];
    }
}

// ---------------- weight prep: fp32 W[k][n] -> bf16 Wt[n][k] for layers 2-4 ------

__global__ void k_prepw(const float* __restrict__ W2, const float* __restrict__ W3,
                        const float* __restrict__ W4, unsigned short* __restrict__ Wt) {
    int idx = blockIdx.x * blockDim.x + threadIdx.x;
    if (idx >= 3 * HD * HD) return;
    int l = idx / (HD * HD), rem = idx % (HD * HD);
    int n = rem >> 7, k = rem & 127;
    const float* W = (l == 0) ? W2 : (l == 1) ? W3 : W4;
    Wt[idx] = f2bf(W[k * HD + n]);
}

// ---------------- GEMMs ----------------

// layer 1: x[N,4] @ W[4,128] -> h bf16 [N,128]
__global__ void k_gemm1(const float* __restrict__ x, const float* __restrict__ W,
                        unsigned short* __restrict__ out, int N) {
    int idx = blockIdx.x * blockDim.x + threadIdx.x;
    if (idx >= N * HD) return;
    int node = idx >> 7, col = idx & 127;
    float4 xv = *(const float4*)&x[node * 4];
    float v = xv.x * W[col] + xv.y * W[128 + col] + xv.z * W[256 + col] + xv.w * W[384 + col];
    out[idx] = f2bf(v);
}

// layers 2-4: A_bf16[N,128] @ W -> h bf16 [N,128], via MFMA 16x16x32
#define LDA 136   // padded LDS row stride (elements)
__global__ __launch_bounds__(256) void k_gemm_mfma(const unsigned short* __restrict__ A,
                                                   const unsigned short* __restrict__ Wt,
                                                   unsigned short* __restrict__ out, int N) {
    __shared__ unsigned short As[128 * LDA];
    __shared__ unsigned short Ws[128 * LDA];
    const int tid = threadIdx.x;
    const int nbase = blockIdx.x * 128;
    const int lane = tid & 63, w = tid >> 6;
    const int l15 = lane & 15, quad = lane >> 4;
    const int koff = quad * 8;

    for (int c = tid; c < 2048; c += 256) {
        int row = c >> 4, k8 = (c & 15) << 3;
        int g = nbase + row;
        uint4 v = make_uint4(0, 0, 0, 0);
        if (g < N) v = *(const uint4*)&A[(size_t)g * HD + k8];
        *(uint4*)&As[row * LDA + k8] = v;
    }
    for (int c = tid; c < 2048; c += 256) {
        int row = c >> 4, k8 = (c & 15) << 3;
        *(uint4*)&Ws[row * LDA + k8] = *(const uint4*)&Wt[row * HD + k8];
    }
    __syncthreads();

    f32x4 acc0[8], acc1[8];
    #pragma unroll
    for (int c = 0; c < 8; ++c) { acc0[c] = (f32x4)(0.f); acc1[c] = (f32x4)(0.f); }

    const int r0 = w * 32 + l15;
    #pragma unroll
    for (int ks = 0; ks < 4; ++ks) {
        bf16x8 a0 = *(const bf16x8*)&As[r0 * LDA + ks * 32 + koff];
        bf16x8 a1 = *(const bf16x8*)&As[(r0 + 16) * LDA + ks * 32 + koff];
        #pragma unroll
        for (int c = 0; c < 8; ++c) {
            bf16x8 b = *(const bf16x8*)&Ws[(c * 16 + l15) * LDA + ks * 32 + koff];
            acc0[c] = __builtin_amdgcn_mfma_f32_16x16x32_bf16(a0, b, acc0[c], 0, 0, 0);
            acc1[c] = __builtin_amdgcn_mfma_f32_16x16x32_bf16(a1, b, acc1[c], 0, 0, 0);
        }
    }

    #pragma unroll
    for (int i = 0; i < 2; ++i) {
        int rowb = nbase + w * 32 + i * 16 + quad * 4;
        #pragma unroll
        for (int c = 0; c < 8; ++c) {
            f32x4 v = i ? acc1[c] : acc0[c];
            int col = c * 16 + l15;
            #pragma unroll
            for (int r = 0; r < 4; ++r) {
                int row = rowb + r;
                if (row < N) out[(size_t)row * HD + col] = f2bf(v[r]);
            }
        }
    }
}

// ---------------- per-node alpha (dot with attention vectors) ----------------
__global__ void k_alpha(const unsigned short* __restrict__ h, const float* __restrict__ asrc,
                        const float* __restrict__ adst, float* __restrict__ oas,
                        float* __restrict__ oad, int N) {
    int n = (blockIdx.x * blockDim.x + threadIdx.x) >> 6;
    int lane = threadIdx.x & 63;
    if (n >= N) return;
    ushort2 uv = *(const ushort2*)&h[(size_t)n * HD + lane * 2];
    float vx = bf2f(uv.x), vy = bf2f(uv.y);
    float2 av = *(const float2*)&asrc[lane * 2];
    float2 dv = *(const float2*)&adst[lane * 2];
    float s = vx * av.x + vy * av.y;
    float t = vx * dv.x + vy * dv.y;
    #pragma unroll
    for (int off = 16; off > 0; off >>= 1) {
        s += __shfl_xor(s, off);
        t += __shfl_xor(t, off);
    }
    if ((lane & 31) == 0) {
        int head = lane >> 5;
        oas[n * 2 + head] = s;
        oad[n * 2 + head] = t;
    }
}

// ---------------- fused edge-softmax + aggregation + bias + relu ----------------
// one wave per node. Pass 1: lane-parallel scores (chunk of <=64 edges) + shuffle
// reductions for max/sum. Pass 2: independent-FMA accumulation with lane-broadcast
// (readlane) of s_j / p_j. Chunk-level online rescale handles degree > 64.
__global__ void k_agg(const unsigned short* __restrict__ h, const float* __restrict__ oas,
                      const float* __restrict__ oad, const int* __restrict__ ptr,
                      const int* __restrict__ csr, const float* __restrict__ bias,
                      unsigned short* __restrict__ out, int N) {
    int n = (blockIdx.x * blockDim.x + threadIdx.x) >> 6;
    int lane = threadIdx.x & 63;
    if (n >= N) return;
    const int head = lane >> 5;
    float2 b2 = *(const float2*)&bias[lane * 2];
    int beg = ptr[n], end = ptr[n + 1];
    if (beg == end) {   // isolated node: out = relu(bias)
        unsigned int packed = (unsigned int)f2bf(fmaxf(b2.x, 0.f)) |
                              ((unsigned int)f2bf(fmaxf(b2.y, 0.f)) << 16);
        *(unsigned int*)&out[(size_t)n * HD + lane * 2] = packed;
        return;
    }
    float2 adn = *(const float2*)&oad[n * 2];
    float m0 = -INFINITY, m1 = -INFINITY, l0 = 0.f, l1 = 0.f;
    float accx = 0.f, accy = 0.f;

    for (int cbeg = beg; cbeg < end; cbeg += 64) {
        int cnt = min(64, end - cbeg);
        // ---- pass 1: lane-parallel scores ----
        int s = 0;
        float e0 = -INFINITY, e1 = -INFINITY;
        if (lane < cnt) {
            s = csr[cbeg + lane];
            float2 as = *(const float2*)&oas[s * 2];
            e0 = as.x + adn.x; e0 = (e0 >= 0.f) ? e0 : NEG_SLOPE * e0;
            e1 = as.y + adn.y; e1 = (e1 >= 0.f) ? e1 : NEG_SLOPE * e1;
        }
        float c0 = e0, c1 = e1;
        #pragma unroll
        for (int off = 32; off > 0; off >>= 1) {
            c0 = fmaxf(c0, __shfl_xor(c0, off));
            c1 = fmaxf(c1, __shfl_xor(c1, off));
        }
        float nm0 = fmaxf(m0, c0), nm1 = fmaxf(m1, c1);
        float sc0 = __expf(m0 - nm0), sc1 = __expf(m1 - nm1);  // first chunk: exp(-inf)=0
        float p0 = (lane < cnt) ? __expf(e0 - nm0) : 0.f;
        float p1 = (lane < cnt) ? __expf(e1 - nm1) : 0.f;
        float s0 = p0, s1 = p1;
        #pragma unroll
        for (int off = 32; off > 0; off >>= 1) {
            s0 += __shfl_xor(s0, off);
            s1 += __shfl_xor(s1, off);
        }
        l0 = l0 * sc0 + s0;
        l1 = l1 * sc1 + s1;
        float scl = head ? sc1 : sc0;
        accx *= scl; accy *= scl;
        m0 = nm0; m1 = nm1;

        // ---- pass 2: independent gather-FMA accumulation ----
        const unsigned short* hb = h + lane * 2;
        for (int j = 0; j < cnt; ++j) {
            int sj = __builtin_amdgcn_readlane(s, j);
            float pj0 = rdlane_f(p0, j);
            float pj1 = rdlane_f(p1, j);
            float pj = head ? pj1 : pj0;
            ushort2 uv = *(const ushort2*)&hb[(size_t)sj * HD];
            accx += pj * bf2f(uv.x);
            accy += pj * bf2f(uv.y);
        }
    }
    float lsel = head ? l1 : l0;
    float inv = 1.f / (lsel + 1e-16f);
    float ox = fmaxf(accx * inv + b2.x, 0.f);
    float oy = fmaxf(accy * inv + b2.y, 0.f);
    unsigned int packed = (unsigned int)f2bf(ox) | ((unsigned int)f2bf(oy) << 16);
    *(unsigned int*)&out[(size_t)n * HD + lane * 2] = packed;
}

// ---------------- pooling (fused graph-size count) ----------------
__global__ void k_pool(const unsigned short* __restrict__ feat, const int* __restrict__ batch,
                       float* __restrict__ pooled, int* __restrict__ gcount, int N) {
    int col = threadIdx.x;
    int n0 = blockIdx.x * 128;
    int n1 = min(n0 + 128, N);
    float acc = 0.f;
    int curg = -1, runlen = 0;
    for (int n = n0; n < n1; ++n) {
        int g = batch[n];
        if (g != curg) {
            if (curg >= 0) {
                atomicAdd(&pooled[curg * HD + col], acc);
                if (col == 0) atomicAdd(&gcount[curg], runlen);
            }
            acc = 0.f; runlen = 0;
            curg = g;
        }
        acc += bf2f(feat[(size_t)n * HD + col]);
        runlen++;
    }
    if (curg >= 0) {
        atomicAdd(&pooled[curg * HD + col], acc);
        if (col == 0) atomicAdd(&gcount[curg], runlen);
    }
}

__global__ void k_final(const float* __restrict__ pooled, const int* __restrict__ gcount,
                        const float* __restrict__ lw, const float* __restrict__ lb,
                        float* __restrict__ out) {
    int tid = threadIdx.x;
    if (tid >= NGRAPH * NCLS) return;
    int g = tid / NCLS, c = tid % NCLS;
    float cnt = fmaxf((float)gcount[g], 1.f);
    const float* p = pooled + g * HD;
    float sum = 0.f;
    for (int k = 0; k < HD; ++k)
        sum += p[k] * lw[k * NCLS + c];
    float z = lb[c] + sum / cnt;
    out[tid] = 1.f / (1.f + __expf(-z));
}

// ---------------- launch ----------------

static inline size_t al256(size_t x) { return (x + 255) & ~(size_t)255; }

extern "C" void kernel_launch(void* const* d_in, const int* in_sizes, int n_in,
                              void* d_out, int out_size, void* d_ws, size_t ws_size,
                              hipStream_t stream) {
    const int N = in_sizes[0] / 4;   // x is [N,4]
    const int E = in_sizes[1] / 2;   // edge_index is [2,E]

    const float* x     = (const float*)d_in[0];
    const int*   esrc  = (const int*)d_in[1];
    const int*   edst  = esrc + E;
    const int*   batch = (const int*)d_in[2];
    const float* Wl[4]  = {(const float*)d_in[3],  (const float*)d_in[7],
                           (const float*)d_in[11], (const float*)d_in[15]};
    const float* asr[4] = {(const float*)d_in[4],  (const float*)d_in[8],
                           (const float*)d_in[12], (const float*)d_in[16]};
    const float* ads[4] = {(const float*)d_in[5],  (const float*)d_in[9],
                           (const float*)d_in[13], (const float*)d_in[17]};
    const float* bs[4]  = {(const float*)d_in[6],  (const float*)d_in[10],
                           (const float*)d_in[14], (const float*)d_in[18]};
    const float* lin_w = (const float*)d_in[19];
    const float* lin_b = (const float*)d_in[20];
    float* out = (float*)d_out;

    // workspace layout (zero-region first)
    char* w = (char*)d_ws;
    size_t off = 0;
    auto alloc = [&](size_t bytes) -> void* {
        void* p = w + off;
        off = al256(off + bytes);
        return p;
    };
    int*   deg    = (int*)alloc((size_t)N * 4);
    int*   fill   = (int*)alloc((size_t)N * 4);
    int*   gcount = (int*)alloc((size_t)NGRAPH * 4);
    float* pooled = (float*)alloc((size_t)NGRAPH * HD * 4);
    size_t zbytes = off;
    int*   ptr    = (int*)alloc((size_t)(N + 1) * 4);
    int*   csr    = (int*)alloc((size_t)E * 4);
    unsigned short* hbuf = (unsigned short*)alloc((size_t)N * HD * 2);
    unsigned short* feat = (unsigned short*)alloc((size_t)N * HD * 2);
    unsigned short* Wt   = (unsigned short*)alloc((size_t)3 * HD * HD * 2);
    float* a_src  = (float*)alloc((size_t)N * 2 * 4);
    float* a_dst  = (float*)alloc((size_t)N * 2 * 4);
    (void)ws_size; (void)n_in; (void)out_size;

    hipMemsetAsync(d_ws, 0, zbytes, stream);

    // weight prep + CSR by dst (reused by all 4 layers)
    k_prepw<<<(3 * HD * HD + 255) / 256, 256, 0, stream>>>(Wl[1], Wl[2], Wl[3], Wt);
    k_deg<<<(E + 255) / 256, 256, 0, stream>>>(edst, deg, E);
    k_scan<<<1, 1024, 0, stream>>>(deg, ptr, N);
    k_scatter<<<(E + 255) / 256, 256, 0, stream>>>(esrc, edst, ptr, fill, csr, E);

    const int node_wave_blocks = (N + 3) / 4;  // one wave per node, 4 waves/block

    for (int layer = 0; layer < 4; ++layer) {
        if (layer == 0)
            k_gemm1<<<(N * HD + 255) / 256, 256, 0, stream>>>(x, Wl[0], hbuf, N);
        else
            k_gemm_mfma<<<(N + 127) / 128, 256, 0, stream>>>(feat, Wt + (size_t)(layer - 1) * HD * HD, hbuf, N);
        k_alpha<<<node_wave_blocks, 256, 0, stream>>>(hbuf, asr[layer], ads[layer], a_src, a_dst, N);
        k_agg<<<node_wave_blocks, 256, 0, stream>>>(hbuf, a_src, a_dst, ptr, csr, bs[layer], feat, N);
    }

    k_pool<<<(N + 127) / 128, 128, 0, stream>>>(feat, batch, pooled, gcount, N);
    k_final<<<1, 320, 0, stream>>>(pooled, gcount, lin_w, lin_b, out);
}

// Round 5
// 446.476 us; speedup vs baseline: 2.5432x; 1.1210x over previous
//
#include <hip/hip_runtime.h>
#include <math.h>

// Problem constants (from reference)
#define NHEAD 2
#define NDIM  64
#define HD    128   // NHEAD*NDIM
#define NGRAPH 64
#define NCLS  5
#define NEG_SLOPE 0.2f

typedef __attribute__((ext_vector_type(8))) short bf16x8;
typedef __attribute__((ext_vector_type(4))) float f32x4;

static __device__ __forceinline__ unsigned short f2bf(float f) {
    unsigned int u = __float_as_uint(f);
    u = (u + 0x7fff + ((u >> 16) & 1)) >> 16;   // round-to-nearest-even
    return (unsigned short)u;
}
static __device__ __forceinline__ float bf2f(unsigned short b) {
    return __uint_as_float((unsigned int)b << 16);
}
static __device__ __forceinline__ float rdlane_f(float v, int j) {
    return __uint_as_float(__builtin_amdgcn_readlane(__float_as_uint(v), j));
}

// ---------------- CSR build ----------------

__global__ void k_deg(const int* __restrict__ dst, int* __restrict__ deg, int E) {
    int i = blockIdx.x * blockDim.x + threadIdx.x;
    if (i < E) atomicAdd(&deg[dst[i]], 1);
}

// hierarchical exclusive scan, phase 1: per-block (2048 elems) local inclusive scan
__global__ __launch_bounds__(256) void k_scan_local(const int* __restrict__ deg,
                                                    int* __restrict__ ptr,
                                                    int* __restrict__ bsum, int n) {
    __shared__ int wsum[4];
    const int tid = threadIdx.x, lane = tid & 63, wid = tid >> 6;
    const int base = blockIdx.x * 2048 + tid * 8;
    int v[8];
    #pragma unroll
    for (int k = 0; k < 8; ++k) {
        int i = base + k;
        v[k] = (i < n) ? deg[i] : 0;
    }
    #pragma unroll
    for (int k = 1; k < 8; ++k) v[k] += v[k - 1];
    int x = v[7];
    #pragma unroll
    for (int off = 1; off < 64; off <<= 1) {
        int t = __shfl_up(x, off, 64);
        if (lane >= off) x += t;
    }
    if (lane == 63) wsum[wid] = x;
    __syncthreads();
    int woff = 0;
    #pragma unroll
    for (int k = 0; k < 4; ++k) woff += (k < wid) ? wsum[k] : 0;
    int texcl = woff + x - v[7];   // exclusive prefix of this thread within block
    #pragma unroll
    for (int k = 0; k < 8; ++k) {
        int i = base + k;
        if (i < n) ptr[i + 1] = texcl + v[k];
    }
    if (tid == 255) bsum[blockIdx.x] = woff + x;   // block total
    if (blockIdx.x == 0 && tid == 0) ptr[0] = 0;
}

// phase 2: one wave scans block sums in place (exclusive)
__global__ void k_scan_bsum(int* __restrict__ bsum, int B) {
    int lane = threadIdx.x;
    int carry = 0;
    for (int base = 0; base < B; base += 64) {
        int i = base + lane;
        int v = (i < B) ? bsum[i] : 0;
        int x = v;
        #pragma unroll
        for (int off = 1; off < 64; off <<= 1) {
            int t = __shfl_up(x, off, 64);
            if (lane >= off) x += t;
        }
        if (i < B) bsum[i] = carry + x - v;
        carry += __shfl(x, 63, 64);
    }
}

// phase 3: add block offsets
__global__ __launch_bounds__(256) void k_scan_add(int* __restrict__ ptr,
                                                  const int* __restrict__ bsum, int n) {
    int off = bsum[blockIdx.x];
    if (off == 0) return;
    const int base = blockIdx.x * 2048 + threadIdx.x * 8;
    #pragma unroll
    for (int k = 0; k < 8; ++k) {
        int i = base + k;
        if (i < n) ptr[i + 1] += off;
    }
}

__global__ void k_scatter(const int* __restrict__ src, const int* __restrict__ dst,
                          const int* __restrict__ ptr, int* __restrict__ fill,
                          int* __restrict__ csr, int E) {
    int i = blockIdx.x * blockDim.x + threadIdx.x;
    if (i < E) {
        int d = dst[i];
        int pos = atomicAdd(&fill[d], 1);
        csr[ptr[d] + pos] = src[i];
    }
}

// ---------------- weight prep: fp32 W[k][n] -> bf16 Wt[n][k] for layers 2-4 ------

__global__ void k_prepw(const float* __restrict__ W2, const float* __restrict__ W3,
                        const float* __restrict__ W4, unsigned short* __restrict__ Wt) {
    int idx = blockIdx.x * blockDim.x + threadIdx.x;
    if (idx >= 3 * HD * HD) return;
    int l = idx / (HD * HD), rem = idx % (HD * HD);
    int n = rem >> 7, k = rem & 127;
    const float* W = (l == 0) ? W2 : (l == 1) ? W3 : W4;
    Wt[idx] = f2bf(W[k * HD + n]);
}

// ---------------- GEMMs ----------------

// layer 1: x[N,4] @ W[4,128] -> h bf16 [N,128]
__global__ void k_gemm1(const float* __restrict__ x, const float* __restrict__ W,
                        unsigned short* __restrict__ out, int N) {
    int idx = blockIdx.x * blockDim.x + threadIdx.x;
    if (idx >= N * HD) return;
    int node = idx >> 7, col = idx & 127;
    float4 xv = *(const float4*)&x[node * 4];
    float v = xv.x * W[col] + xv.y * W[128 + col] + xv.z * W[256 + col] + xv.w * W[384 + col];
    out[idx] = f2bf(v);
}

// layers 2-4: A_bf16[N,128] @ W -> h bf16 [N,128], via MFMA 16x16x32.
// Epilogue fuses alpha_src/alpha_dst row-dots (16-lane shfl reduction).
#define LDA 136   // padded LDS row stride (elements)
__global__ __launch_bounds__(256) void k_gemm_mfma(const unsigned short* __restrict__ A,
                                                   const unsigned short* __restrict__ Wt,
                                                   const float* __restrict__ asrc,
                                                   const float* __restrict__ adst,
                                                   unsigned short* __restrict__ out,
                                                   float* __restrict__ oas,
                                                   float* __restrict__ oad, int N) {
    __shared__ unsigned short As[128 * LDA];
    __shared__ unsigned short Ws[128 * LDA];
    const int tid = threadIdx.x;
    const int nbase = blockIdx.x * 128;
    const int lane = tid & 63, w = tid >> 6;
    const int l15 = lane & 15, quad = lane >> 4;
    const int koff = quad * 8;

    for (int c = tid; c < 2048; c += 256) {
        int row = c >> 4, k8 = (c & 15) << 3;
        int g = nbase + row;
        uint4 v = make_uint4(0, 0, 0, 0);
        if (g < N) v = *(const uint4*)&A[(size_t)g * HD + k8];
        *(uint4*)&As[row * LDA + k8] = v;
    }
    for (int c = tid; c < 2048; c += 256) {
        int row = c >> 4, k8 = (c & 15) << 3;
        *(uint4*)&Ws[row * LDA + k8] = *(const uint4*)&Wt[row * HD + k8];
    }
    // attention vectors for this lane's 8 columns (col = c*16 + l15)
    float av[8], dv[8];
    #pragma unroll
    for (int c = 0; c < 8; ++c) {
        av[c] = asrc[c * 16 + l15];
        dv[c] = adst[c * 16 + l15];
    }
    __syncthreads();

    f32x4 acc0[8], acc1[8];
    #pragma unroll
    for (int c = 0; c < 8; ++c) { acc0[c] = (f32x4)(0.f); acc1[c] = (f32x4)(0.f); }

    const int r0 = w * 32 + l15;
    #pragma unroll
    for (int ks = 0; ks < 4; ++ks) {
        bf16x8 a0 = *(const bf16x8*)&As[r0 * LDA + ks * 32 + koff];
        bf16x8 a1 = *(const bf16x8*)&As[(r0 + 16) * LDA + ks * 32 + koff];
        #pragma unroll
        for (int c = 0; c < 8; ++c) {
            bf16x8 b = *(const bf16x8*)&Ws[(c * 16 + l15) * LDA + ks * 32 + koff];
            acc0[c] = __builtin_amdgcn_mfma_f32_16x16x32_bf16(a0, b, acc0[c], 0, 0, 0);
            acc1[c] = __builtin_amdgcn_mfma_f32_16x16x32_bf16(a1, b, acc1[c], 0, 0, 0);
        }
    }

    // D layout: row = i*16 + quad*4 + reg, col = c*16 + l15
    #pragma unroll
    for (int i = 0; i < 2; ++i) {
        int rowb = nbase + w * 32 + i * 16 + quad * 4;
        // h store
        #pragma unroll
        for (int c = 0; c < 8; ++c) {
            f32x4 v = i ? acc1[c] : acc0[c];
            int col = c * 16 + l15;
            #pragma unroll
            for (int r = 0; r < 4; ++r) {
                int row = rowb + r;
                if (row < N) out[(size_t)row * HD + col] = f2bf(v[r]);
            }
        }
        // fused alpha: per row, head0 = cols 0..63 (c<4), head1 = cols 64..127
        #pragma unroll
        for (int r = 0; r < 4; ++r) {
            float ps0 = 0.f, ps1 = 0.f, pd0 = 0.f, pd1 = 0.f;
            #pragma unroll
            for (int c = 0; c < 4; ++c) {
                float hv = i ? acc1[c][r] : acc0[c][r];
                ps0 += hv * av[c]; pd0 += hv * dv[c];
            }
            #pragma unroll
            for (int c = 4; c < 8; ++c) {
                float hv = i ? acc1[c][r] : acc0[c][r];
                ps1 += hv * av[c]; pd1 += hv * dv[c];
            }
            #pragma unroll
            for (int off = 1; off < 16; off <<= 1) {
                ps0 += __shfl_xor(ps0, off);
                ps1 += __shfl_xor(ps1, off);
                pd0 += __shfl_xor(pd0, off);
                pd1 += __shfl_xor(pd1, off);
            }
            int row = rowb + r;
            if (l15 == 0 && row < N) {
                *(float2*)&oas[row * 2] = make_float2(ps0, ps1);
                *(float2*)&oad[row * 2] = make_float2(pd0, pd1);
            }
        }
    }
}

// ---------------- per-node alpha (layer 1 only) ----------------
__global__ void k_alpha(const unsigned short* __restrict__ h, const float* __restrict__ asrc,
                        const float* __restrict__ adst, float* __restrict__ oas,
                        float* __restrict__ oad, int N) {
    int n = (blockIdx.x * blockDim.x + threadIdx.x) >> 6;
    int lane = threadIdx.x & 63;
    if (n >= N) return;
    ushort2 uv = *(const ushort2*)&h[(size_t)n * HD + lane * 2];
    float vx = bf2f(uv.x), vy = bf2f(uv.y);
    float2 av = *(const float2*)&asrc[lane * 2];
    float2 dv = *(const float2*)&adst[lane * 2];
    float s = vx * av.x + vy * av.y;
    float t = vx * dv.x + vy * dv.y;
    #pragma unroll
    for (int off = 16; off > 0; off >>= 1) {
        s += __shfl_xor(s, off);
        t += __shfl_xor(t, off);
    }
    if ((lane & 31) == 0) {
        int head = lane >> 5;
        oas[n * 2 + head] = s;
        oad[n * 2 + head] = t;
    }
}

// ---------------- fused edge-softmax + aggregation + bias + relu ----------------
__global__ void k_agg(const unsigned short* __restrict__ h, const float* __restrict__ oas,
                      const float* __restrict__ oad, const int* __restrict__ ptr,
                      const int* __restrict__ csr, const float* __restrict__ bias,
                      unsigned short* __restrict__ out, int N) {
    int n = (blockIdx.x * blockDim.x + threadIdx.x) >> 6;
    int lane = threadIdx.x & 63;
    if (n >= N) return;
    const int head = lane >> 5;
    float2 b2 = *(const float2*)&bias[lane * 2];
    int beg = ptr[n], end = ptr[n + 1];
    if (beg == end) {   // isolated node: out = relu(bias)
        unsigned int packed = (unsigned int)f2bf(fmaxf(b2.x, 0.f)) |
                              ((unsigned int)f2bf(fmaxf(b2.y, 0.f)) << 16);
        *(unsigned int*)&out[(size_t)n * HD + lane * 2] = packed;
        return;
    }
    float2 adn = *(const float2*)&oad[n * 2];
    float m0 = -INFINITY, m1 = -INFINITY, l0 = 0.f, l1 = 0.f;
    float accx = 0.f, accy = 0.f;

    for (int cbeg = beg; cbeg < end; cbeg += 64) {
        int cnt = min(64, end - cbeg);
        // ---- pass 1: lane-parallel scores ----
        int s = 0;
        float e0 = -INFINITY, e1 = -INFINITY;
        if (lane < cnt) {
            s = csr[cbeg + lane];
            float2 as = *(const float2*)&oas[s * 2];
            e0 = as.x + adn.x; e0 = (e0 >= 0.f) ? e0 : NEG_SLOPE * e0;
            e1 = as.y + adn.y; e1 = (e1 >= 0.f) ? e1 : NEG_SLOPE * e1;
        }
        float c0 = e0, c1 = e1;
        #pragma unroll
        for (int off = 32; off > 0; off >>= 1) {
            c0 = fmaxf(c0, __shfl_xor(c0, off));
            c1 = fmaxf(c1, __shfl_xor(c1, off));
        }
        float nm0 = fmaxf(m0, c0), nm1 = fmaxf(m1, c1);
        float sc0 = __expf(m0 - nm0), sc1 = __expf(m1 - nm1);  // first chunk: exp(-inf)=0
        float p0 = (lane < cnt) ? __expf(e0 - nm0) : 0.f;
        float p1 = (lane < cnt) ? __expf(e1 - nm1) : 0.f;
        float s0 = p0, s1 = p1;
        #pragma unroll
        for (int off = 32; off > 0; off >>= 1) {
            s0 += __shfl_xor(s0, off);
            s1 += __shfl_xor(s1, off);
        }
        l0 = l0 * sc0 + s0;
        l1 = l1 * sc1 + s1;
        float scl = head ? sc1 : sc0;
        accx *= scl; accy *= scl;
        m0 = nm0; m1 = nm1;

        // ---- pass 2: independent gather-FMA accumulation ----
        const unsigned short* hb = h + lane * 2;
        for (int j = 0; j < cnt; ++j) {
            int sj = __builtin_amdgcn_readlane(s, j);
            float pj0 = rdlane_f(p0, j);
            float pj1 = rdlane_f(p1, j);
            float pj = head ? pj1 : pj0;
            ushort2 uv = *(const ushort2*)&hb[(size_t)sj * HD];
            accx += pj * bf2f(uv.x);
            accy += pj * bf2f(uv.y);
        }
    }
    float lsel = head ? l1 : l0;
    float inv = 1.f / (lsel + 1e-16f);
    float ox = fmaxf(accx * inv + b2.x, 0.f);
    float oy = fmaxf(accy * inv + b2.y, 0.f);
    unsigned int packed = (unsigned int)f2bf(ox) | ((unsigned int)f2bf(oy) << 16);
    *(unsigned int*)&out[(size_t)n * HD + lane * 2] = packed;
}

// ---------------- pooling (fused graph-size count) ----------------
__global__ void k_pool(const unsigned short* __restrict__ feat, const int* __restrict__ batch,
                       float* __restrict__ pooled, int* __restrict__ gcount, int N) {
    int col = threadIdx.x;
    int n0 = blockIdx.x * 128;
    int n1 = min(n0 + 128, N);
    float acc = 0.f;
    int curg = -1, runlen = 0;
    for (int n = n0; n < n1; ++n) {
        int g = batch[n];
        if (g != curg) {
            if (curg >= 0) {
                atomicAdd(&pooled[curg * HD + col], acc);
                if (col == 0) atomicAdd(&gcount[curg], runlen);
            }
            acc = 0.f; runlen = 0;
            curg = g;
        }
        acc += bf2f(feat[(size_t)n * HD + col]);
        runlen++;
    }
    if (curg >= 0) {
        atomicAdd(&pooled[curg * HD + col], acc);
        if (col == 0) atomicAdd(&gcount[curg], runlen);
    }
}

__global__ void k_final(const float* __restrict__ pooled, const int* __restrict__ gcount,
                        const float* __restrict__ lw, const float* __restrict__ lb,
                        float* __restrict__ out) {
    int tid = threadIdx.x;
    if (tid >= NGRAPH * NCLS) return;
    int g = tid / NCLS, c = tid % NCLS;
    float cnt = fmaxf((float)gcount[g], 1.f);
    const float* p = pooled + g * HD;
    float sum = 0.f;
    for (int k = 0; k < HD; ++k)
        sum += p[k] * lw[k * NCLS + c];
    float z = lb[c] + sum / cnt;
    out[tid] = 1.f / (1.f + __expf(-z));
}

// ---------------- launch ----------------

static inline size_t al256(size_t x) { return (x + 255) & ~(size_t)255; }

extern "C" void kernel_launch(void* const* d_in, const int* in_sizes, int n_in,
                              void* d_out, int out_size, void* d_ws, size_t ws_size,
                              hipStream_t stream) {
    const int N = in_sizes[0] / 4;   // x is [N,4]
    const int E = in_sizes[1] / 2;   // edge_index is [2,E]

    const float* x     = (const float*)d_in[0];
    const int*   esrc  = (const int*)d_in[1];
    const int*   edst  = esrc + E;
    const int*   batch = (const int*)d_in[2];
    const float* Wl[4]  = {(const float*)d_in[3],  (const float*)d_in[7],
                           (const float*)d_in[11], (const float*)d_in[15]};
    const float* asr[4] = {(const float*)d_in[4],  (const float*)d_in[8],
                           (const float*)d_in[12], (const float*)d_in[16]};
    const float* ads[4] = {(const float*)d_in[5],  (const float*)d_in[9],
                           (const float*)d_in[13], (const float*)d_in[17]};
    const float* bs[4]  = {(const float*)d_in[6],  (const float*)d_in[10],
                           (const float*)d_in[14], (const float*)d_in[18]};
    const float* lin_w = (const float*)d_in[19];
    const float* lin_b = (const float*)d_in[20];
    float* out = (float*)d_out;

    // workspace layout (zero-region first)
    char* w = (char*)d_ws;
    size_t off = 0;
    auto alloc = [&](size_t bytes) -> void* {
        void* p = w + off;
        off = al256(off + bytes);
        return p;
    };
    int*   deg    = (int*)alloc((size_t)N * 4);
    int*   fill   = (int*)alloc((size_t)N * 4);
    int*   gcount = (int*)alloc((size_t)NGRAPH * 4);
    float* pooled = (float*)alloc((size_t)NGRAPH * HD * 4);
    size_t zbytes = off;
    int*   ptr    = (int*)alloc((size_t)(N + 1) * 4);
    int*   bsum   = (int*)alloc((size_t)1024 * 4);
    int*   csr    = (int*)alloc((size_t)E * 4);
    unsigned short* hbuf = (unsigned short*)alloc((size_t)N * HD * 2);
    unsigned short* feat = (unsigned short*)alloc((size_t)N * HD * 2);
    unsigned short* Wt   = (unsigned short*)alloc((size_t)3 * HD * HD * 2);
    float* a_src  = (float*)alloc((size_t)N * 2 * 4);
    float* a_dst  = (float*)alloc((size_t)N * 2 * 4);
    (void)ws_size; (void)n_in; (void)out_size;

    hipMemsetAsync(d_ws, 0, zbytes, stream);

    // weight prep + CSR by dst (reused by all 4 layers)
    k_prepw<<<(3 * HD * HD + 255) / 256, 256, 0, stream>>>(Wl[1], Wl[2], Wl[3], Wt);
    k_deg<<<(E + 255) / 256, 256, 0, stream>>>(edst, deg, E);
    const int SB = (N + 2047) / 2048;
    k_scan_local<<<SB, 256, 0, stream>>>(deg, ptr, bsum, N);
    k_scan_bsum<<<1, 64, 0, stream>>>(bsum, SB);
    k_scan_add<<<SB, 256, 0, stream>>>(ptr, bsum, N);
    k_scatter<<<(E + 255) / 256, 256, 0, stream>>>(esrc, edst, ptr, fill, csr, E);

    const int node_wave_blocks = (N + 3) / 4;  // one wave per node, 4 waves/block

    for (int layer = 0; layer < 4; ++layer) {
        if (layer == 0) {
            k_gemm1<<<(N * HD + 255) / 256, 256, 0, stream>>>(x, Wl[0], hbuf, N);
            k_alpha<<<node_wave_blocks, 256, 0, stream>>>(hbuf, asr[0], ads[0], a_src, a_dst, N);
        } else {
            k_gemm_mfma<<<(N + 127) / 128, 256, 0, stream>>>(
                feat, Wt + (size_t)(layer - 1) * HD * HD,
                asr[layer], ads[layer], hbuf, a_src, a_dst, N);
        }
        k_agg<<<node_wave_blocks, 256, 0, stream>>>(hbuf, a_src, a_dst, ptr, csr, bs[layer], feat, N);
    }

    k_pool<<<(N + 127) / 128, 128, 0, stream>>>(feat, batch, pooled, gcount, N);
    k_final<<<1, 320, 0, stream>>>(pooled, gcount, lin_w, lin_b, out);
}

// Round 6
// 406.060 us; speedup vs baseline: 2.7963x; 1.0995x over previous
//
#include <hip/hip_runtime.h>
#include <math.h>

// Problem constants (from reference)
#define NHEAD 2
#define NDIM  64
#define HD    128   // NHEAD*NDIM
#define NGRAPH 64
#define NCLS  5
#define NEG_SLOPE 0.2f

typedef __attribute__((ext_vector_type(8))) short bf16x8;
typedef __attribute__((ext_vector_type(4))) float f32x4;

static __device__ __forceinline__ unsigned short f2bf(float f) {
    unsigned int u = __float_as_uint(f);
    u = (u + 0x7fff + ((u >> 16) & 1)) >> 16;   // round-to-nearest-even
    return (unsigned short)u;
}
static __device__ __forceinline__ float bf2f(unsigned short b) {
    return __uint_as_float((unsigned int)b << 16);
}

// ---------------- CSR build ----------------

__global__ void k_deg(const int* __restrict__ dst, int* __restrict__ deg, int E) {
    int i = blockIdx.x * blockDim.x + threadIdx.x;
    if (i < E) atomicAdd(&deg[dst[i]], 1);
}

// hierarchical exclusive scan, phase 1: per-block (2048 elems) local inclusive scan
__global__ __launch_bounds__(256) void k_scan_local(const int* __restrict__ deg,
                                                    int* __restrict__ ptr,
                                                    int* __restrict__ bsum, int n) {
    __shared__ int wsum[4];
    const int tid = threadIdx.x, lane = tid & 63, wid = tid >> 6;
    const int base = blockIdx.x * 2048 + tid * 8;
    int v[8];
    #pragma unroll
    for (int k = 0; k < 8; ++k) {
        int i = base + k;
        v[k] = (i < n) ? deg[i] : 0;
    }
    #pragma unroll
    for (int k = 1; k < 8; ++k) v[k] += v[k - 1];
    int x = v[7];
    #pragma unroll
    for (int off = 1; off < 64; off <<= 1) {
        int t = __shfl_up(x, off, 64);
        if (lane >= off) x += t;
    }
    if (lane == 63) wsum[wid] = x;
    __syncthreads();
    int woff = 0;
    #pragma unroll
    for (int k = 0; k < 4; ++k) woff += (k < wid) ? wsum[k] : 0;
    int texcl = woff + x - v[7];   // exclusive prefix of this thread within block
    #pragma unroll
    for (int k = 0; k < 8; ++k) {
        int i = base + k;
        if (i < n) ptr[i + 1] = texcl + v[k];
    }
    if (tid == 255) bsum[blockIdx.x] = woff + x;   // block total
    if (blockIdx.x == 0 && tid == 0) ptr[0] = 0;
}

// phase 2: one wave scans block sums in place (exclusive)
__global__ void k_scan_bsum(int* __restrict__ bsum, int B) {
    int lane = threadIdx.x;
    int carry = 0;
    for (int base = 0; base < B; base += 64) {
        int i = base + lane;
        int v = (i < B) ? bsum[i] : 0;
        int x = v;
        #pragma unroll
        for (int off = 1; off < 64; off <<= 1) {
            int t = __shfl_up(x, off, 64);
            if (lane >= off) x += t;
        }
        if (i < B) bsum[i] = carry + x - v;
        carry += __shfl(x, 63, 64);
    }
}

// phase 3: add block offsets
__global__ __launch_bounds__(256) void k_scan_add(int* __restrict__ ptr,
                                                  const int* __restrict__ bsum, int n) {
    int off = bsum[blockIdx.x];
    if (off == 0) return;
    const int base = blockIdx.x * 2048 + threadIdx.x * 8;
    #pragma unroll
    for (int k = 0; k < 8; ++k) {
        int i = base + k;
        if (i < n) ptr[i + 1] += off;
    }
}

__global__ void k_scatter(const int* __restrict__ src, const int* __restrict__ dst,
                          const int* __restrict__ ptr, int* __restrict__ fill,
                          int* __restrict__ csr, int E) {
    int i = blockIdx.x * blockDim.x + threadIdx.x;
    if (i < E) {
        int d = dst[i];
        int pos = atomicAdd(&fill[d], 1);
        csr[ptr[d] + pos] = src[i];
    }
}

// ---------------- weight prep: fp32 W[k][n] -> bf16 Wt[n][k] for layers 2-4 ------

__global__ void k_prepw(const float* __restrict__ W2, const float* __restrict__ W3,
                        const float* __restrict__ W4, unsigned short* __restrict__ Wt) {
    int idx = blockIdx.x * blockDim.x + threadIdx.x;
    if (idx >= 3 * HD * HD) return;
    int l = idx / (HD * HD), rem = idx % (HD * HD);
    int n = rem >> 7, k = rem & 127;
    const float* W = (l == 0) ? W2 : (l == 1) ? W3 : W4;
    Wt[idx] = f2bf(W[k * HD + n]);
}

// ---------------- GEMMs ----------------

// layer 1: x[N,4] @ W[4,128] -> h bf16 [N,128]
__global__ void k_gemm1(const float* __restrict__ x, const float* __restrict__ W,
                        unsigned short* __restrict__ out, int N) {
    int idx = blockIdx.x * blockDim.x + threadIdx.x;
    if (idx >= N * HD) return;
    int node = idx >> 7, col = idx & 127;
    float4 xv = *(const float4*)&x[node * 4];
    float v = xv.x * W[col] + xv.y * W[128 + col] + xv.z * W[256 + col] + xv.w * W[384 + col];
    out[idx] = f2bf(v);
}

// layers 2-4: A_bf16[N,128] @ W -> h bf16 [N,128], via MFMA 16x16x32.
// Epilogue fuses alpha_src/alpha_dst row-dots (16-lane shfl reduction).
#define LDA 136   // padded LDS row stride (elements)
__global__ __launch_bounds__(256) void k_gemm_mfma(const unsigned short* __restrict__ A,
                                                   const unsigned short* __restrict__ Wt,
                                                   const float* __restrict__ asrc,
                                                   const float* __restrict__ adst,
                                                   unsigned short* __restrict__ out,
                                                   float* __restrict__ oas,
                                                   float* __restrict__ oad, int N) {
    __shared__ unsigned short As[128 * LDA];
    __shared__ unsigned short Ws[128 * LDA];
    const int tid = threadIdx.x;
    const int nbase = blockIdx.x * 128;
    const int lane = tid & 63, w = tid >> 6;
    const int l15 = lane & 15, quad = lane >> 4;
    const int koff = quad * 8;

    for (int c = tid; c < 2048; c += 256) {
        int row = c >> 4, k8 = (c & 15) << 3;
        int g = nbase + row;
        uint4 v = make_uint4(0, 0, 0, 0);
        if (g < N) v = *(const uint4*)&A[(size_t)g * HD + k8];
        *(uint4*)&As[row * LDA + k8] = v;
    }
    for (int c = tid; c < 2048; c += 256) {
        int row = c >> 4, k8 = (c & 15) << 3;
        *(uint4*)&Ws[row * LDA + k8] = *(const uint4*)&Wt[row * HD + k8];
    }
    // attention vectors for this lane's 8 columns (col = c*16 + l15)
    float av[8], dv[8];
    #pragma unroll
    for (int c = 0; c < 8; ++c) {
        av[c] = asrc[c * 16 + l15];
        dv[c] = adst[c * 16 + l15];
    }
    __syncthreads();

    f32x4 acc0[8], acc1[8];
    #pragma unroll
    for (int c = 0; c < 8; ++c) { acc0[c] = (f32x4)(0.f); acc1[c] = (f32x4)(0.f); }

    const int r0 = w * 32 + l15;
    #pragma unroll
    for (int ks = 0; ks < 4; ++ks) {
        bf16x8 a0 = *(const bf16x8*)&As[r0 * LDA + ks * 32 + koff];
        bf16x8 a1 = *(const bf16x8*)&As[(r0 + 16) * LDA + ks * 32 + koff];
        #pragma unroll
        for (int c = 0; c < 8; ++c) {
            bf16x8 b = *(const bf16x8*)&Ws[(c * 16 + l15) * LDA + ks * 32 + koff];
            acc0[c] = __builtin_amdgcn_mfma_f32_16x16x32_bf16(a0, b, acc0[c], 0, 0, 0);
            acc1[c] = __builtin_amdgcn_mfma_f32_16x16x32_bf16(a1, b, acc1[c], 0, 0, 0);
        }
    }

    // D layout: row = i*16 + quad*4 + reg, col = c*16 + l15
    #pragma unroll
    for (int i = 0; i < 2; ++i) {
        int rowb = nbase + w * 32 + i * 16 + quad * 4;
        // h store
        #pragma unroll
        for (int c = 0; c < 8; ++c) {
            f32x4 v = i ? acc1[c] : acc0[c];
            int col = c * 16 + l15;
            #pragma unroll
            for (int r = 0; r < 4; ++r) {
                int row = rowb + r;
                if (row < N) out[(size_t)row * HD + col] = f2bf(v[r]);
            }
        }
        // fused alpha: per row, head0 = cols 0..63 (c<4), head1 = cols 64..127
        #pragma unroll
        for (int r = 0; r < 4; ++r) {
            float ps0 = 0.f, ps1 = 0.f, pd0 = 0.f, pd1 = 0.f;
            #pragma unroll
            for (int c = 0; c < 4; ++c) {
                float hv = i ? acc1[c][r] : acc0[c][r];
                ps0 += hv * av[c]; pd0 += hv * dv[c];
            }
            #pragma unroll
            for (int c = 4; c < 8; ++c) {
                float hv = i ? acc1[c][r] : acc0[c][r];
                ps1 += hv * av[c]; pd1 += hv * dv[c];
            }
            #pragma unroll
            for (int off = 1; off < 16; off <<= 1) {
                ps0 += __shfl_xor(ps0, off);
                ps1 += __shfl_xor(ps1, off);
                pd0 += __shfl_xor(pd0, off);
                pd1 += __shfl_xor(pd1, off);
            }
            int row = rowb + r;
            if (l15 == 0 && row < N) {
                *(float2*)&oas[row * 2] = make_float2(ps0, ps1);
                *(float2*)&oad[row * 2] = make_float2(pd0, pd1);
            }
        }
    }
}

// ---------------- per-node alpha (layer 1 only) ----------------
__global__ void k_alpha(const unsigned short* __restrict__ h, const float* __restrict__ asrc,
                        const float* __restrict__ adst, float* __restrict__ oas,
                        float* __restrict__ oad, int N) {
    int n = (blockIdx.x * blockDim.x + threadIdx.x) >> 6;
    int lane = threadIdx.x & 63;
    if (n >= N) return;
    ushort2 uv = *(const ushort2*)&h[(size_t)n * HD + lane * 2];
    float vx = bf2f(uv.x), vy = bf2f(uv.y);
    float2 av = *(const float2*)&asrc[lane * 2];
    float2 dv = *(const float2*)&adst[lane * 2];
    float s = vx * av.x + vy * av.y;
    float t = vx * dv.x + vy * dv.y;
    #pragma unroll
    for (int off = 16; off > 0; off >>= 1) {
        s += __shfl_xor(s, off);
        t += __shfl_xor(t, off);
    }
    if ((lane & 31) == 0) {
        int head = lane >> 5;
        oas[n * 2 + head] = s;
        oad[n * 2 + head] = t;
    }
}

// ---------------- fused edge-softmax + aggregation + bias + relu ----------------
// one wave per node. Pass 1: lane-parallel scores + shuffle reductions.
// Pass 2: 4 edges/iteration, quarter-wave per edge, 16B loads; lane sub of quad q
// holds dims [8*sub, 8*sub+8) of edge (j+q)'s h-row. Cross-quarter reduce at end.
__global__ void k_agg(const unsigned short* __restrict__ h, const float* __restrict__ oas,
                      const float* __restrict__ oad, const int* __restrict__ ptr,
                      const int* __restrict__ csr, const float* __restrict__ bias,
                      unsigned short* __restrict__ out, int N) {
    int n = (blockIdx.x * blockDim.x + threadIdx.x) >> 6;
    int lane = threadIdx.x & 63;
    if (n >= N) return;
    int beg = ptr[n], end = ptr[n + 1];
    if (beg == end) {   // isolated node: out = relu(bias)
        float2 b2 = *(const float2*)&bias[lane * 2];
        unsigned int packed = (unsigned int)f2bf(fmaxf(b2.x, 0.f)) |
                              ((unsigned int)f2bf(fmaxf(b2.y, 0.f)) << 16);
        *(unsigned int*)&out[(size_t)n * HD + lane * 2] = packed;
        return;
    }
    const int quad = lane >> 4, sub = lane & 15;
    const int hsel = sub >> 3;   // head covered by this lane's pass-2 dims
    float2 adn = *(const float2*)&oad[n * 2];
    float m0 = -INFINITY, m1 = -INFINITY, l0 = 0.f, l1 = 0.f;
    float acc[8];
    #pragma unroll
    for (int k = 0; k < 8; ++k) acc[k] = 0.f;

    for (int cbeg = beg; cbeg < end; cbeg += 64) {
        int cnt = min(64, end - cbeg);
        // ---- pass 1: lane-parallel scores ----
        int s = 0;
        float e0 = -INFINITY, e1 = -INFINITY;
        if (lane < cnt) {
            s = csr[cbeg + lane];
            float2 as = *(const float2*)&oas[s * 2];
            e0 = as.x + adn.x; e0 = (e0 >= 0.f) ? e0 : NEG_SLOPE * e0;
            e1 = as.y + adn.y; e1 = (e1 >= 0.f) ? e1 : NEG_SLOPE * e1;
        }
        float c0 = e0, c1 = e1;
        #pragma unroll
        for (int off = 32; off > 0; off >>= 1) {
            c0 = fmaxf(c0, __shfl_xor(c0, off));
            c1 = fmaxf(c1, __shfl_xor(c1, off));
        }
        float nm0 = fmaxf(m0, c0), nm1 = fmaxf(m1, c1);
        float sc0 = __expf(m0 - nm0), sc1 = __expf(m1 - nm1);  // first chunk: exp(-inf)=0
        float p0 = (lane < cnt) ? __expf(e0 - nm0) : 0.f;
        float p1 = (lane < cnt) ? __expf(e1 - nm1) : 0.f;
        float s0 = p0, s1 = p1;
        #pragma unroll
        for (int off = 32; off > 0; off >>= 1) {
            s0 += __shfl_xor(s0, off);
            s1 += __shfl_xor(s1, off);
        }
        l0 = l0 * sc0 + s0;
        l1 = l1 * sc1 + s1;
        m0 = nm0; m1 = nm1;
        float scl = hsel ? sc1 : sc0;
        #pragma unroll
        for (int k = 0; k < 8; ++k) acc[k] *= scl;

        // ---- pass 2: 4 edges per iteration, 16B gathers ----
        for (int j = 0; j < cnt; j += 4) {
            int jq = j + quad;                    // <= 63 always
            int sj = __shfl(s, jq);               // 0 for jq >= cnt (safe)
            float pa = __shfl(p0, jq);
            float pb = __shfl(p1, jq);
            float pj = hsel ? pb : pa;            // 0 for jq >= cnt
            uint4 hv = *(const uint4*)&h[(size_t)sj * HD + sub * 8];
            #pragma unroll
            for (int k = 0; k < 4; ++k) {
                unsigned int u = (&hv.x)[k];
                acc[2 * k]     += pj * __uint_as_float(u << 16);
                acc[2 * k + 1] += pj * __uint_as_float(u & 0xffff0000u);
            }
        }
    }
    // combine the four quarters
    #pragma unroll
    for (int k = 0; k < 8; ++k) {
        acc[k] += __shfl_xor(acc[k], 16);
        acc[k] += __shfl_xor(acc[k], 32);
    }
    if (quad == 0) {
        float lsel = hsel ? l1 : l0;
        float inv = 1.f / (lsel + 1e-16f);
        float4 ba = *(const float4*)&bias[sub * 8];
        float4 bb = *(const float4*)&bias[sub * 8 + 4];
        float o[8];
        o[0] = fmaxf(acc[0] * inv + ba.x, 0.f);
        o[1] = fmaxf(acc[1] * inv + ba.y, 0.f);
        o[2] = fmaxf(acc[2] * inv + ba.z, 0.f);
        o[3] = fmaxf(acc[3] * inv + ba.w, 0.f);
        o[4] = fmaxf(acc[4] * inv + bb.x, 0.f);
        o[5] = fmaxf(acc[5] * inv + bb.y, 0.f);
        o[6] = fmaxf(acc[6] * inv + bb.z, 0.f);
        o[7] = fmaxf(acc[7] * inv + bb.w, 0.f);
        uint4 pk;
        pk.x = (unsigned int)f2bf(o[0]) | ((unsigned int)f2bf(o[1]) << 16);
        pk.y = (unsigned int)f2bf(o[2]) | ((unsigned int)f2bf(o[3]) << 16);
        pk.z = (unsigned int)f2bf(o[4]) | ((unsigned int)f2bf(o[5]) << 16);
        pk.w = (unsigned int)f2bf(o[6]) | ((unsigned int)f2bf(o[7]) << 16);
        *(uint4*)&out[(size_t)n * HD + sub * 8] = pk;
    }
}

// ---------------- pooling (fused graph-size count) ----------------
__global__ void k_pool(const unsigned short* __restrict__ feat, const int* __restrict__ batch,
                       float* __restrict__ pooled, int* __restrict__ gcount, int N) {
    int col = threadIdx.x;
    int n0 = blockIdx.x * 128;
    int n1 = min(n0 + 128, N);
    float acc = 0.f;
    int curg = -1, runlen = 0;
    for (int n = n0; n < n1; ++n) {
        int g = batch[n];
        if (g != curg) {
            if (curg >= 0) {
                atomicAdd(&pooled[curg * HD + col], acc);
                if (col == 0) atomicAdd(&gcount[curg], runlen);
            }
            acc = 0.f; runlen = 0;
            curg = g;
        }
        acc += bf2f(feat[(size_t)n * HD + col]);
        runlen++;
    }
    if (curg >= 0) {
        atomicAdd(&pooled[curg * HD + col], acc);
        if (col == 0) atomicAdd(&gcount[curg], runlen);
    }
}

__global__ void k_final(const float* __restrict__ pooled, const int* __restrict__ gcount,
                        const float* __restrict__ lw, const float* __restrict__ lb,
                        float* __restrict__ out) {
    int tid = threadIdx.x;
    if (tid >= NGRAPH * NCLS) return;
    int g = tid / NCLS, c = tid % NCLS;
    float cnt = fmaxf((float)gcount[g], 1.f);
    const float* p = pooled + g * HD;
    float sum = 0.f;
    for (int k = 0; k < HD; ++k)
        sum += p[k] * lw[k * NCLS + c];
    float z = lb[c] + sum / cnt;
    out[tid] = 1.f / (1.f + __expf(-z));
}

// ---------------- launch ----------------

static inline size_t al256(size_t x) { return (x + 255) & ~(size_t)255; }

extern "C" void kernel_launch(void* const* d_in, const int* in_sizes, int n_in,
                              void* d_out, int out_size, void* d_ws, size_t ws_size,
                              hipStream_t stream) {
    const int N = in_sizes[0] / 4;   // x is [N,4]
    const int E = in_sizes[1] / 2;   // edge_index is [2,E]

    const float* x     = (const float*)d_in[0];
    const int*   esrc  = (const int*)d_in[1];
    const int*   edst  = esrc + E;
    const int*   batch = (const int*)d_in[2];
    const float* Wl[4]  = {(const float*)d_in[3],  (const float*)d_in[7],
                           (const float*)d_in[11], (const float*)d_in[15]};
    const float* asr[4] = {(const float*)d_in[4],  (const float*)d_in[8],
                           (const float*)d_in[12], (const float*)d_in[16]};
    const float* ads[4] = {(const float*)d_in[5],  (const float*)d_in[9],
                           (const float*)d_in[13], (const float*)d_in[17]};
    const float* bs[4]  = {(const float*)d_in[6],  (const float*)d_in[10],
                           (const float*)d_in[14], (const float*)d_in[18]};
    const float* lin_w = (const float*)d_in[19];
    const float* lin_b = (const float*)d_in[20];
    float* out = (float*)d_out;

    // workspace layout (zero-region first)
    char* w = (char*)d_ws;
    size_t off = 0;
    auto alloc = [&](size_t bytes) -> void* {
        void* p = w + off;
        off = al256(off + bytes);
        return p;
    };
    int*   deg    = (int*)alloc((size_t)N * 4);
    int*   fill   = (int*)alloc((size_t)N * 4);
    int*   gcount = (int*)alloc((size_t)NGRAPH * 4);
    float* pooled = (float*)alloc((size_t)NGRAPH * HD * 4);
    size_t zbytes = off;
    int*   ptr    = (int*)alloc((size_t)(N + 1) * 4);
    int*   bsum   = (int*)alloc((size_t)1024 * 4);
    int*   csr    = (int*)alloc((size_t)E * 4);
    unsigned short* hbuf = (unsigned short*)alloc((size_t)N * HD * 2);
    unsigned short* feat = (unsigned short*)alloc((size_t)N * HD * 2);
    unsigned short* Wt   = (unsigned short*)alloc((size_t)3 * HD * HD * 2);
    float* a_src  = (float*)alloc((size_t)N * 2 * 4);
    float* a_dst  = (float*)alloc((size_t)N * 2 * 4);
    (void)ws_size; (void)n_in; (void)out_size;

    hipMemsetAsync(d_ws, 0, zbytes, stream);

    // weight prep + CSR by dst (reused by all 4 layers)
    k_prepw<<<(3 * HD * HD + 255) / 256, 256, 0, stream>>>(Wl[1], Wl[2], Wl[3], Wt);
    k_deg<<<(E + 255) / 256, 256, 0, stream>>>(edst, deg, E);
    const int SB = (N + 2047) / 2048;
    k_scan_local<<<SB, 256, 0, stream>>>(deg, ptr, bsum, N);
    k_scan_bsum<<<1, 64, 0, stream>>>(bsum, SB);
    k_scan_add<<<SB, 256, 0, stream>>>(ptr, bsum, N);
    k_scatter<<<(E + 255) / 256, 256, 0, stream>>>(esrc, edst, ptr, fill, csr, E);

    const int node_wave_blocks = (N + 3) / 4;  // one wave per node, 4 waves/block

    for (int layer = 0; layer < 4; ++layer) {
        if (layer == 0) {
            k_gemm1<<<(N * HD + 255) / 256, 256, 0, stream>>>(x, Wl[0], hbuf, N);
            k_alpha<<<node_wave_blocks, 256, 0, stream>>>(hbuf, asr[0], ads[0], a_src, a_dst, N);
        } else {
            k_gemm_mfma<<<(N + 127) / 128, 256, 0, stream>>>(
                feat, Wt + (size_t)(layer - 1) * HD * HD,
                asr[layer], ads[layer], hbuf, a_src, a_dst, N);
        }
        k_agg<<<node_wave_blocks, 256, 0, stream>>>(hbuf, a_src, a_dst, ptr, csr, bs[layer], feat, N);
    }

    k_pool<<<(N + 127) / 128, 128, 0, stream>>>(feat, batch, pooled, gcount, N);
    k_final<<<1, 320, 0, stream>>>(pooled, gcount, lin_w, lin_b, out);
}